// Round 1
// baseline (290.861 us; speedup 1.0000x reference)
//
#include <hip/hip_runtime.h>
#include <math.h>

#define NB 8
#define NT 2048
#define NC 1024
#define DK 64
#define BT (NB*NT)

typedef unsigned short ushort_t;
typedef unsigned int uint_t;

__device__ __forceinline__ float bf2f(uint_t u) {
    union { uint_t i; float f; } v;
    v.i = u << 16;
    return v.f;
}
__device__ __forceinline__ ushort_t f2bf(float f) {
    union { float f; uint_t i; } v; v.f = f;
    uint_t x = v.i;
    return (ushort_t)((x + 0x7fffu + ((x >> 16) & 1u)) >> 16);
}

// ---------------------------------------------------------------------------
// Kernel 1: QKV projection.  Y = X @ W + b, stored as bf16 into ws.
// Grid: (BT/64, 3) blocks of 256 threads. blockIdx.y selects Q/K/V.
// 64x64 output tile, BK=32, 4x4 register blocking per thread.
// ---------------------------------------------------------------------------
__global__ __launch_bounds__(256) void qkv_proj_kernel(
    const float* __restrict__ X,
    const float* __restrict__ Wq, const float* __restrict__ bq,
    const float* __restrict__ Wk, const float* __restrict__ bk,
    const float* __restrict__ Wv, const float* __restrict__ bv,
    ushort_t* __restrict__ QKV)
{
    const int which = blockIdx.y;
    const float* W    = (which == 0) ? Wq : (which == 1) ? Wk : Wv;
    const float* bias = (which == 0) ? bq : (which == 1) ? bk : bv;
    ushort_t* Y = QKV + (size_t)which * BT * DK;

    // pad 36 / 68: keeps float4 LDS reads 16B-aligned, <=2-way bank conflict
    __shared__ float Xs[64][36];
    __shared__ float Ws[32][68];

    const int t  = threadIdx.x;
    const int r0 = blockIdx.x * 64;
    const int rl = (t >> 4) * 4;    // 0..60 step 4
    const int cl = (t & 15) * 4;    // 0..60 step 4

    float acc[4][4] = {};

    for (int k0 = 0; k0 < NC; k0 += 32) {
        {
            const int row = t >> 3;          // 0..31
            const int c4  = (t & 7) * 4;     // 0..28
            *reinterpret_cast<float4*>(&Xs[row][c4]) =
                *reinterpret_cast<const float4*>(&X[(size_t)(r0 + row) * NC + k0 + c4]);
            *reinterpret_cast<float4*>(&Xs[row + 32][c4]) =
                *reinterpret_cast<const float4*>(&X[(size_t)(r0 + row + 32) * NC + k0 + c4]);
            const int kk  = t >> 4;          // 0..15
            const int c4w = (t & 15) * 4;    // 0..60
            *reinterpret_cast<float4*>(&Ws[kk][c4w]) =
                *reinterpret_cast<const float4*>(&W[(size_t)(k0 + kk) * DK + c4w]);
            *reinterpret_cast<float4*>(&Ws[kk + 16][c4w]) =
                *reinterpret_cast<const float4*>(&W[(size_t)(k0 + kk + 16) * DK + c4w]);
        }
        __syncthreads();

        #pragma unroll
        for (int kk4 = 0; kk4 < 32; kk4 += 4) {
            float4 a0 = *reinterpret_cast<const float4*>(&Xs[rl + 0][kk4]);
            float4 a1 = *reinterpret_cast<const float4*>(&Xs[rl + 1][kk4]);
            float4 a2 = *reinterpret_cast<const float4*>(&Xs[rl + 2][kk4]);
            float4 a3 = *reinterpret_cast<const float4*>(&Xs[rl + 3][kk4]);
            float4 w0 = *reinterpret_cast<const float4*>(&Ws[kk4 + 0][cl]);
            float4 w1 = *reinterpret_cast<const float4*>(&Ws[kk4 + 1][cl]);
            float4 w2 = *reinterpret_cast<const float4*>(&Ws[kk4 + 2][cl]);
            float4 w3 = *reinterpret_cast<const float4*>(&Ws[kk4 + 3][cl]);

            #define PROJ_STEP(WW, COMP)                                              \
            {                                                                        \
                float t0 = a0.COMP, t1 = a1.COMP, t2 = a2.COMP, t3 = a3.COMP;        \
                acc[0][0] = fmaf(t0, WW.x, acc[0][0]);                               \
                acc[0][1] = fmaf(t0, WW.y, acc[0][1]);                               \
                acc[0][2] = fmaf(t0, WW.z, acc[0][2]);                               \
                acc[0][3] = fmaf(t0, WW.w, acc[0][3]);                               \
                acc[1][0] = fmaf(t1, WW.x, acc[1][0]);                               \
                acc[1][1] = fmaf(t1, WW.y, acc[1][1]);                               \
                acc[1][2] = fmaf(t1, WW.z, acc[1][2]);                               \
                acc[1][3] = fmaf(t1, WW.w, acc[1][3]);                               \
                acc[2][0] = fmaf(t2, WW.x, acc[2][0]);                               \
                acc[2][1] = fmaf(t2, WW.y, acc[2][1]);                               \
                acc[2][2] = fmaf(t2, WW.z, acc[2][2]);                               \
                acc[2][3] = fmaf(t2, WW.w, acc[2][3]);                               \
                acc[3][0] = fmaf(t3, WW.x, acc[3][0]);                               \
                acc[3][1] = fmaf(t3, WW.y, acc[3][1]);                               \
                acc[3][2] = fmaf(t3, WW.z, acc[3][2]);                               \
                acc[3][3] = fmaf(t3, WW.w, acc[3][3]);                               \
            }
            PROJ_STEP(w0, x)
            PROJ_STEP(w1, y)
            PROJ_STEP(w2, z)
            PROJ_STEP(w3, w)
            #undef PROJ_STEP
        }
        __syncthreads();
    }

    const float b0 = bias[cl + 0], b1 = bias[cl + 1], b2 = bias[cl + 2], b3 = bias[cl + 3];
    #pragma unroll
    for (int i = 0; i < 4; ++i) {
        const size_t off = (size_t)(r0 + rl + i) * DK + cl;
        ushort4 s;
        s.x = f2bf(acc[i][0] + b0);
        s.y = f2bf(acc[i][1] + b1);
        s.z = f2bf(acc[i][2] + b2);
        s.w = f2bf(acc[i][3] + b3);
        *reinterpret_cast<ushort4*>(&Y[off]) = s;
    }
}

// ---------------------------------------------------------------------------
// Kernel 2: causal flash attention (online softmax), f32 accumulation.
// Grid: 512 blocks x 256 threads. Block -> (batch = b&7, q-tile of 32 rows).
// Tile map jj<32 ? jj : 95-jj pairs long+short causal strips per CU.
// 8 threads per q-row; each thread owns 8 score columns and 8 output dims.
// ---------------------------------------------------------------------------
__global__ __launch_bounds__(256) void attn_kernel(
    const ushort_t* __restrict__ QKV, float* __restrict__ Out)
{
    const ushort_t* Qw = QKV;
    const ushort_t* Kw = QKV + (size_t)BT * DK;
    const ushort_t* Vw = QKV + (size_t)2 * BT * DK;

    __shared__ float Ks[64][68];
    __shared__ float Vs[64][68];

    const int t      = threadIdx.x;
    const int batch  = blockIdx.x & 7;
    const int jj     = blockIdx.x >> 3;
    const int qt     = (jj < 32) ? jj : (95 - jj);
    const int r0     = qt * 32;
    const int c8     = t & 7;
    const int row    = r0 + (t >> 3);
    const int lane   = t & 63;
    const int lanebase = lane & ~7;

    // Q row (64 bf16) -> 64 f32 registers
    float q[64];
    {
        const uint4* qp = reinterpret_cast<const uint4*>(Qw + ((size_t)batch * NT + row) * DK);
        #pragma unroll
        for (int i = 0; i < 8; ++i) {
            uint4 u = qp[i];
            q[i*8+0] = bf2f(u.x & 0xffffu); q[i*8+1] = bf2f(u.x >> 16);
            q[i*8+2] = bf2f(u.y & 0xffffu); q[i*8+3] = bf2f(u.y >> 16);
            q[i*8+4] = bf2f(u.z & 0xffffu); q[i*8+5] = bf2f(u.z >> 16);
            q[i*8+6] = bf2f(u.w & 0xffffu); q[i*8+7] = bf2f(u.w >> 16);
        }
    }

    float out[8] = {0.f,0.f,0.f,0.f,0.f,0.f,0.f,0.f};
    float m = -INFINITY, l = 0.0f;

    const int nkt = (qt >> 1) + 1;
    for (int kt = 0; kt < nkt; ++kt) {
        const int s0 = kt * 64;
        // stage K,V tile (64x64 bf16 -> f32 LDS)
        {
            const int srow = t >> 2;         // 0..63
            const int ch   = (t & 3) * 16;   // 0,16,32,48
            const size_t goff = ((size_t)batch * NT + s0 + srow) * DK + ch;
            const uint4* kp = reinterpret_cast<const uint4*>(Kw + goff);
            const uint4* vp = reinterpret_cast<const uint4*>(Vw + goff);
            #pragma unroll
            for (int hh = 0; hh < 2; ++hh) {
                uint4 u = kp[hh];
                float4 f0 = { bf2f(u.x & 0xffffu), bf2f(u.x >> 16),
                              bf2f(u.y & 0xffffu), bf2f(u.y >> 16) };
                float4 f1 = { bf2f(u.z & 0xffffu), bf2f(u.z >> 16),
                              bf2f(u.w & 0xffffu), bf2f(u.w >> 16) };
                *reinterpret_cast<float4*>(&Ks[srow][ch + hh*8 + 0]) = f0;
                *reinterpret_cast<float4*>(&Ks[srow][ch + hh*8 + 4]) = f1;
                uint4 v = vp[hh];
                float4 g0 = { bf2f(v.x & 0xffffu), bf2f(v.x >> 16),
                              bf2f(v.y & 0xffffu), bf2f(v.y >> 16) };
                float4 g1 = { bf2f(v.z & 0xffffu), bf2f(v.z >> 16),
                              bf2f(v.w & 0xffffu), bf2f(v.w >> 16) };
                *reinterpret_cast<float4*>(&Vs[srow][ch + hh*8 + 0]) = g0;
                *reinterpret_cast<float4*>(&Vs[srow][ch + hh*8 + 4]) = g1;
            }
        }
        __syncthreads();

        // QK^T: 8 scores per thread
        float p[8];
        float mt = -INFINITY;
        #pragma unroll
        for (int i = 0; i < 8; ++i) {
            const int sl = c8 + 8*i;
            float sc = 0.0f;
            #pragma unroll
            for (int kk = 0; kk < 16; ++kk) {
                float4 kv = *reinterpret_cast<const float4*>(&Ks[sl][kk*4]);
                sc = fmaf(q[kk*4+0], kv.x, sc);
                sc = fmaf(q[kk*4+1], kv.y, sc);
                sc = fmaf(q[kk*4+2], kv.z, sc);
                sc = fmaf(q[kk*4+3], kv.w, sc);
            }
            sc *= 0.125f;                       // 1/sqrt(64)
            if (s0 + sl > row) sc = -INFINITY;  // causal mask
            p[i] = sc;
            mt = fmaxf(mt, sc);
        }
        #pragma unroll
        for (int off = 1; off < 8; off <<= 1) mt = fmaxf(mt, __shfl_xor(mt, off, 64));

        const float m_new = fmaxf(m, mt);
        const float scale_old = __expf(m - m_new);   // 0 when m == -inf
        float lt = 0.0f;
        #pragma unroll
        for (int i = 0; i < 8; ++i) { p[i] = __expf(p[i] - m_new); lt += p[i]; }
        #pragma unroll
        for (int off = 1; off < 8; off <<= 1) lt += __shfl_xor(lt, off, 64);
        l = l * scale_old + lt;
        m = m_new;
        #pragma unroll
        for (int j = 0; j < 8; ++j) out[j] *= scale_old;

        // PV: broadcast p across the 8-lane row group, accumulate 8 dims
        #pragma unroll
        for (int i = 0; i < 8; ++i) {
            #pragma unroll
            for (int c = 0; c < 8; ++c) {
                const float pv = __shfl(p[i], lanebase + c, 64);
                const int sl = c + 8*i;
                const float* vrow = &Vs[sl][c8 * 8];
                float4 v0 = *reinterpret_cast<const float4*>(vrow);
                float4 v1 = *reinterpret_cast<const float4*>(vrow + 4);
                out[0] = fmaf(pv, v0.x, out[0]);
                out[1] = fmaf(pv, v0.y, out[1]);
                out[2] = fmaf(pv, v0.z, out[2]);
                out[3] = fmaf(pv, v0.w, out[3]);
                out[4] = fmaf(pv, v1.x, out[4]);
                out[5] = fmaf(pv, v1.y, out[5]);
                out[6] = fmaf(pv, v1.z, out[6]);
                out[7] = fmaf(pv, v1.w, out[7]);
            }
        }
        __syncthreads();
    }

    const float inv_l = 1.0f / l;
    float4 o0 = { out[0]*inv_l, out[1]*inv_l, out[2]*inv_l, out[3]*inv_l };
    float4 o1 = { out[4]*inv_l, out[5]*inv_l, out[6]*inv_l, out[7]*inv_l };
    float* op = &Out[((size_t)batch * NT + row) * DK + c8 * 8];
    *reinterpret_cast<float4*>(op)     = o0;
    *reinterpret_cast<float4*>(op + 4) = o1;
}

extern "C" void kernel_launch(void* const* d_in, const int* in_sizes, int n_in,
                              void* d_out, int out_size, void* d_ws, size_t ws_size,
                              hipStream_t stream) {
    const float* X  = (const float*)d_in[0];
    const float* Wq = (const float*)d_in[1];
    const float* bq = (const float*)d_in[2];
    const float* Wk = (const float*)d_in[3];
    const float* bk = (const float*)d_in[4];
    const float* Wv = (const float*)d_in[5];
    const float* bv = (const float*)d_in[6];
    float* Out = (float*)d_out;
    ushort_t* QKV = (ushort_t*)d_ws;   // Q | K | V, each BT*DK bf16 (6 MB total)

    dim3 g1(BT / 64, 3);
    qkv_proj_kernel<<<g1, 256, 0, stream>>>(X, Wq, bq, Wk, bk, Wv, bv, QKV);
    attn_kernel<<<512, 256, 0, stream>>>(QKV, Out);
}

// Round 3
// 161.517 us; speedup vs baseline: 1.8008x; 1.8008x over previous
//
#include <hip/hip_runtime.h>
#include <math.h>

#define NB 8
#define NT 2048
#define NC 1024
#define DK 64
#define BT (NB*NT)

typedef unsigned short ushort_t;
typedef unsigned int uint_t;
typedef __attribute__((ext_vector_type(8))) short short8;
typedef __attribute__((ext_vector_type(4))) float f32x4;

__device__ __forceinline__ float bf2f(uint_t u) {
    union { uint_t i; float f; } v;
    v.i = u << 16;
    return v.f;
}
__device__ __forceinline__ ushort_t f2bf(float f) {
    union { float f; uint_t i; } v; v.f = f;
    uint_t x = v.i;
    return (ushort_t)((x + 0x7fffu + ((x >> 16) & 1u)) >> 16);
}

// ---------------------------------------------------------------------------
// Kernel 1: QKV projection.  Y = X @ W + b, stored as bf16 into ws.
// (unchanged from round 1 — ~76us; MFMA rewrite is a later move)
// ---------------------------------------------------------------------------
__global__ __launch_bounds__(256) void qkv_proj_kernel(
    const float* __restrict__ X,
    const float* __restrict__ Wq, const float* __restrict__ bq,
    const float* __restrict__ Wk, const float* __restrict__ bk,
    const float* __restrict__ Wv, const float* __restrict__ bv,
    ushort_t* __restrict__ QKV)
{
    const int which = blockIdx.y;
    const float* W    = (which == 0) ? Wq : (which == 1) ? Wk : Wv;
    const float* bias = (which == 0) ? bq : (which == 1) ? bk : bv;
    ushort_t* Y = QKV + (size_t)which * BT * DK;

    __shared__ float Xs[64][36];
    __shared__ float Ws[32][68];

    const int t  = threadIdx.x;
    const int r0 = blockIdx.x * 64;
    const int rl = (t >> 4) * 4;
    const int cl = (t & 15) * 4;

    float acc[4][4] = {};

    for (int k0 = 0; k0 < NC; k0 += 32) {
        {
            const int row = t >> 3;
            const int c4  = (t & 7) * 4;
            *reinterpret_cast<float4*>(&Xs[row][c4]) =
                *reinterpret_cast<const float4*>(&X[(size_t)(r0 + row) * NC + k0 + c4]);
            *reinterpret_cast<float4*>(&Xs[row + 32][c4]) =
                *reinterpret_cast<const float4*>(&X[(size_t)(r0 + row + 32) * NC + k0 + c4]);
            const int kk  = t >> 4;
            const int c4w = (t & 15) * 4;
            *reinterpret_cast<float4*>(&Ws[kk][c4w]) =
                *reinterpret_cast<const float4*>(&W[(size_t)(k0 + kk) * DK + c4w]);
            *reinterpret_cast<float4*>(&Ws[kk + 16][c4w]) =
                *reinterpret_cast<const float4*>(&W[(size_t)(k0 + kk + 16) * DK + c4w]);
        }
        __syncthreads();

        #pragma unroll
        for (int kk4 = 0; kk4 < 32; kk4 += 4) {
            float4 a0 = *reinterpret_cast<const float4*>(&Xs[rl + 0][kk4]);
            float4 a1 = *reinterpret_cast<const float4*>(&Xs[rl + 1][kk4]);
            float4 a2 = *reinterpret_cast<const float4*>(&Xs[rl + 2][kk4]);
            float4 a3 = *reinterpret_cast<const float4*>(&Xs[rl + 3][kk4]);
            float4 w0 = *reinterpret_cast<const float4*>(&Ws[kk4 + 0][cl]);
            float4 w1 = *reinterpret_cast<const float4*>(&Ws[kk4 + 1][cl]);
            float4 w2 = *reinterpret_cast<const float4*>(&Ws[kk4 + 2][cl]);
            float4 w3 = *reinterpret_cast<const float4*>(&Ws[kk4 + 3][cl]);

            #define PROJ_STEP(WW, COMP)                                              \
            {                                                                        \
                float t0 = a0.COMP, t1 = a1.COMP, t2 = a2.COMP, t3 = a3.COMP;        \
                acc[0][0] = fmaf(t0, WW.x, acc[0][0]);                               \
                acc[0][1] = fmaf(t0, WW.y, acc[0][1]);                               \
                acc[0][2] = fmaf(t0, WW.z, acc[0][2]);                               \
                acc[0][3] = fmaf(t0, WW.w, acc[0][3]);                               \
                acc[1][0] = fmaf(t1, WW.x, acc[1][0]);                               \
                acc[1][1] = fmaf(t1, WW.y, acc[1][1]);                               \
                acc[1][2] = fmaf(t1, WW.z, acc[1][2]);                               \
                acc[1][3] = fmaf(t1, WW.w, acc[1][3]);                               \
                acc[2][0] = fmaf(t2, WW.x, acc[2][0]);                               \
                acc[2][1] = fmaf(t2, WW.y, acc[2][1]);                               \
                acc[2][2] = fmaf(t2, WW.z, acc[2][2]);                               \
                acc[2][3] = fmaf(t2, WW.w, acc[2][3]);                               \
                acc[3][0] = fmaf(t3, WW.x, acc[3][0]);                               \
                acc[3][1] = fmaf(t3, WW.y, acc[3][1]);                               \
                acc[3][2] = fmaf(t3, WW.z, acc[3][2]);                               \
                acc[3][3] = fmaf(t3, WW.w, acc[3][3]);                               \
            }
            PROJ_STEP(w0, x)
            PROJ_STEP(w1, y)
            PROJ_STEP(w2, z)
            PROJ_STEP(w3, w)
            #undef PROJ_STEP
        }
        __syncthreads();
    }

    const float b0 = bias[cl + 0], b1 = bias[cl + 1], b2 = bias[cl + 2], b3 = bias[cl + 3];
    #pragma unroll
    for (int i = 0; i < 4; ++i) {
        const size_t off = (size_t)(r0 + rl + i) * DK + cl;
        ushort4 s;
        s.x = f2bf(acc[i][0] + b0);
        s.y = f2bf(acc[i][1] + b1);
        s.z = f2bf(acc[i][2] + b2);
        s.w = f2bf(acc[i][3] + b3);
        *reinterpret_cast<ushort4*>(&Y[off]) = s;
    }
}

// ---------------------------------------------------------------------------
// Kernel 2: causal flash attention on MFMA (bf16 in, f32 accum).
// Grid 256 = (8 batch) x (32 q-tiles of 64 rows), 256 threads = 4 waves.
// Wave w owns rows [r0+16w, r0+16w+16). k-tile = 64 keys.
// mfma_f32_16x16x32_bf16 layouts (m89-verified):
//   A: row=lane&15, k=(lane>>4)*8+i   B: col=lane&15, k=(lane>>4)*8+i
//   C/D: col=lane&15, row=(lane>>4)*4+reg
// LDS: K row-major [64][72], V transposed [64][72] (stride 72 bf16 = 144B:
// 16B-aligned b128 + bank-spread), P per-wave [16][72].
// ---------------------------------------------------------------------------
__global__ __launch_bounds__(256) void attn_mfma_kernel(
    const ushort_t* __restrict__ QKV, float* __restrict__ Out)
{
    const ushort_t* Qw = QKV;
    const ushort_t* Kw = QKV + (size_t)BT * DK;
    const ushort_t* Vw = QKV + (size_t)2 * BT * DK;

    __shared__ ushort_t Ks[2][64 * 72];
    __shared__ ushort_t Vt[2][64 * 72];
    __shared__ ushort_t Pl[4][16 * 72];

    const int t     = threadIdx.x;
    const int w     = t >> 6;
    const int lane  = t & 63;
    const int g     = lane >> 4;
    const int col   = lane & 15;
    const int batch = blockIdx.x & 7;          // batch <-> XCD: K/V L2-resident
    const int qt    = 31 - (blockIdx.x >> 3);  // longest blocks first
    const int r0    = qt * 64;

    // Q fragments held in registers for the whole kernel
    short8 qf[2];
    {
        const ushort_t* Qrow = Qw + ((size_t)(batch * NT) + r0 + w * 16 + col) * DK;
        qf[0] = *reinterpret_cast<const short8*>(Qrow + 8 * g);
        qf[1] = *reinterpret_cast<const short8*>(Qrow + 32 + 8 * g);
    }

    f32x4 Oa[4];
    #pragma unroll
    for (int dt = 0; dt < 4; ++dt) Oa[dt] = (f32x4){0.f, 0.f, 0.f, 0.f};
    float m[4] = {-INFINITY, -INFINITY, -INFINITY, -INFINITY};
    float l[4] = {0.f, 0.f, 0.f, 0.f};

    const int srow = t >> 2;       // 0..63 : staging row
    const int seg  = t & 3;        // 16-ushort segment within row

    uint4 kreg[2], vreg[2];

    auto LOADR = [&](int kt) {
        const size_t go = ((size_t)(batch * NT) + kt * 64 + srow) * DK + seg * 16;
        const uint4* kp = reinterpret_cast<const uint4*>(Kw + go);
        kreg[0] = kp[0]; kreg[1] = kp[1];
        const uint4* vp = reinterpret_cast<const uint4*>(Vw + go);
        vreg[0] = vp[0]; vreg[1] = vp[1];
    };
    auto WRITES = [&](int b) {
        *reinterpret_cast<uint4*>(&Ks[b][srow * 72 + seg * 16])     = kreg[0];
        *reinterpret_cast<uint4*>(&Ks[b][srow * 72 + seg * 16 + 8]) = kreg[1];
        const uint_t* vr = reinterpret_cast<const uint_t*>(vreg);
        #pragma unroll
        for (int i = 0; i < 8; ++i) {
            const uint_t u = vr[i];
            Vt[b][(seg * 16 + 2 * i)     * 72 + srow] = (ushort_t)(u & 0xffffu);
            Vt[b][(seg * 16 + 2 * i + 1) * 72 + srow] = (ushort_t)(u >> 16);
        }
    };

    const int nkt = qt + 1;
    LOADR(0);
    WRITES(0);

    for (int kt = 0; kt < nkt; ++kt) {
        const int cur = kt & 1;
        if (kt + 1 < nkt) LOADR(kt + 1);   // prefetch: latency hides under barrier+compute
        __syncthreads();                   // buf[cur] ready

        const ushort_t* KsB = Ks[cur];
        const ushort_t* VtB = Vt[cur];

        // ---- QK^T : S (16 x 64) ----
        f32x4 sa[4];
        #pragma unroll
        for (int tj = 0; tj < 4; ++tj) sa[tj] = (f32x4){0.f, 0.f, 0.f, 0.f};
        #pragma unroll
        for (int tj = 0; tj < 4; ++tj) {
            const ushort_t* kb = &KsB[(col + 16 * tj) * 72 + 8 * g];
            short8 kf0 = *reinterpret_cast<const short8*>(kb);
            short8 kf1 = *reinterpret_cast<const short8*>(kb + 32);
            sa[tj] = __builtin_amdgcn_mfma_f32_16x16x32_bf16(qf[0], kf0, sa[tj], 0, 0, 0);
            sa[tj] = __builtin_amdgcn_mfma_f32_16x16x32_bf16(qf[1], kf1, sa[tj], 0, 0, 0);
        }

        float sv[4][4];
        #pragma unroll
        for (int tj = 0; tj < 4; ++tj)
            #pragma unroll
            for (int r = 0; r < 4; ++r) sv[tj][r] = sa[tj][r] * 0.125f;

        if (kt == qt) {  // diagonal tile: causal mask
            const int rowb = r0 + 16 * w + 4 * g;
            const int s0   = kt * 64;
            #pragma unroll
            for (int tj = 0; tj < 4; ++tj) {
                const int key = s0 + col + 16 * tj;
                #pragma unroll
                for (int r = 0; r < 4; ++r)
                    if (key > rowb + r) sv[tj][r] = -INFINITY;
            }
        }

        // ---- online softmax (rows owned per reg; 16-lane group reduce) ----
        float mt[4];
        #pragma unroll
        for (int r = 0; r < 4; ++r)
            mt[r] = fmaxf(fmaxf(sv[0][r], sv[1][r]), fmaxf(sv[2][r], sv[3][r]));
        #pragma unroll
        for (int off = 1; off < 16; off <<= 1)
            #pragma unroll
            for (int r = 0; r < 4; ++r)
                mt[r] = fmaxf(mt[r], __shfl_xor(mt[r], off, 16));

        float sc_old[4], lt[4], pb[4][4];
        #pragma unroll
        for (int r = 0; r < 4; ++r) {
            const float mn = fmaxf(m[r], mt[r]);
            sc_old[r] = __expf(m[r] - mn);
            m[r] = mn;
            lt[r] = 0.f;
        }
        #pragma unroll
        for (int tj = 0; tj < 4; ++tj)
            #pragma unroll
            for (int r = 0; r < 4; ++r) {
                pb[tj][r] = __expf(sv[tj][r] - m[r]);
                lt[r] += pb[tj][r];
            }
        #pragma unroll
        for (int off = 1; off < 16; off <<= 1)
            #pragma unroll
            for (int r = 0; r < 4; ++r) lt[r] += __shfl_xor(lt[r], off, 16);
        #pragma unroll
        for (int r = 0; r < 4; ++r) l[r] = l[r] * sc_old[r] + lt[r];
        #pragma unroll
        for (int dt = 0; dt < 4; ++dt)
            #pragma unroll
            for (int r = 0; r < 4; ++r) Oa[dt][r] *= sc_old[r];

        // ---- P -> bf16 -> wave-private LDS -> A fragments ----
        ushort_t* Pw = Pl[w];
        #pragma unroll
        for (int tj = 0; tj < 4; ++tj)
            #pragma unroll
            for (int r = 0; r < 4; ++r)
                Pw[(4 * g + r) * 72 + col + 16 * tj] = f2bf(pb[tj][r]);

        // ---- PV : O += P (16x64) @ V (64x64) ----
        #pragma unroll
        for (int c = 0; c < 2; ++c) {
            short8 pf = *reinterpret_cast<const short8*>(&Pw[col * 72 + 32 * c + 8 * g]);
            #pragma unroll
            for (int dt = 0; dt < 4; ++dt) {
                short8 vf = *reinterpret_cast<const short8*>(
                    &VtB[(col + 16 * dt) * 72 + 32 * c + 8 * g]);
                Oa[dt] = __builtin_amdgcn_mfma_f32_16x16x32_bf16(pf, vf, Oa[dt], 0, 0, 0);
            }
        }

        if (kt + 1 < nkt) WRITES(cur ^ 1);  // other buffer: no reader conflict
    }

    // ---- epilogue ----
    #pragma unroll
    for (int r = 0; r < 4; ++r) {
        const float inv = 1.0f / l[r];
        const int row = r0 + 16 * w + 4 * g + r;
        float* op = Out + ((size_t)(batch * NT) + row) * DK + col;
        #pragma unroll
        for (int dt = 0; dt < 4; ++dt) op[16 * dt] = Oa[dt][r] * inv;
    }
}

extern "C" void kernel_launch(void* const* d_in, const int* in_sizes, int n_in,
                              void* d_out, int out_size, void* d_ws, size_t ws_size,
                              hipStream_t stream) {
    const float* X  = (const float*)d_in[0];
    const float* Wq = (const float*)d_in[1];
    const float* bq = (const float*)d_in[2];
    const float* Wk = (const float*)d_in[3];
    const float* bk = (const float*)d_in[4];
    const float* Wv = (const float*)d_in[5];
    const float* bv = (const float*)d_in[6];
    float* Out = (float*)d_out;
    ushort_t* QKV = (ushort_t*)d_ws;   // Q | K | V, each BT*DK bf16 (6 MB total)

    dim3 g1(BT / 64, 3);
    qkv_proj_kernel<<<g1, 256, 0, stream>>>(X, Wq, bq, Wk, bk, Wv, bv, QKV);
    attn_mfma_kernel<<<256, 256, 0, stream>>>(QKV, Out);
}

// Round 4
// 111.299 us; speedup vs baseline: 2.6133x; 1.4512x over previous
//
#include <hip/hip_runtime.h>
#include <math.h>

#define NB 8
#define NT 2048
#define NC 1024
#define DK 64
#define BT (NB*NT)

typedef unsigned short ushort_t;
typedef unsigned int uint_t;
typedef __attribute__((ext_vector_type(8))) short short8;
typedef __attribute__((ext_vector_type(4))) float f32x4;

__device__ __forceinline__ float bf2f(uint_t u) {
    union { uint_t i; float f; } v;
    v.i = u << 16;
    return v.f;
}
__device__ __forceinline__ ushort_t f2bf(float f) {
    union { float f; uint_t i; } v; v.f = f;
    uint_t x = v.i;
    return (ushort_t)((x + 0x7fffu + ((x >> 16) & 1u)) >> 16);
}

// ---------------------------------------------------------------------------
// Kernel 0: W transpose+cast prep.  Wt[192][1024] bf16, n-major, stored in
// d_out scratch (393 KB << 4 MB; attn kernel later overwrites all of d_out).
// Row n: 0-63 -> Wq col n, 64-127 -> Wk, 128-191 -> Wv.  Wt[n][k] = W[k][n&63].
// Coalesced 16B writes; strided f32 reads hit L2 (W = 786 KB, L2-resident).
// ---------------------------------------------------------------------------
__global__ __launch_bounds__(256) void wt_prep_kernel(
    const float* __restrict__ Wq, const float* __restrict__ Wk,
    const float* __restrict__ Wv, ushort_t* __restrict__ WtG)
{
    const int tg = blockIdx.x * 256 + threadIdx.x;   // 0..24575
    const int n  = tg >> 7;                          // 0..191
    const int k0 = (tg & 127) * 8;
    const float* W = (n < 64) ? Wq : (n < 128) ? Wk : Wv;
    const int nc = n & 63;
    ushort_t o[8];
    #pragma unroll
    for (int j = 0; j < 8; ++j) o[j] = f2bf(W[(size_t)(k0 + j) * DK + nc]);
    *reinterpret_cast<uint4*>(&WtG[n * NC + k0]) = *reinterpret_cast<uint4*>(o);
}

// ---------------------------------------------------------------------------
// Kernel 1: QKV projection on MFMA.  Y = X @ W + b -> bf16 QKV in ws.
// Grid 256 = M-tiles of 64 rows (X read exactly once); 4 waves, wave w owns
// cols [48w, 48w+48) (3 coltiles -> B-fragments unshared across waves).
// Per wave per K-step(64): 24 MFMA vs 14 ds_read_b128.
// Reg-staged double buffer: load next K-tile to regs before the barrier,
// ds_write after compute.  LDS stride 72 bf16 (144B): <=2-way conflicts.
// ---------------------------------------------------------------------------
__global__ __launch_bounds__(256) void qkv_mfma_kernel(
    const float* __restrict__ X, const ushort_t* __restrict__ WtG,
    const float* __restrict__ bq, const float* __restrict__ bk,
    const float* __restrict__ bv, ushort_t* __restrict__ QKV)
{
    __shared__ ushort_t Xs[2][64 * 72];
    __shared__ ushort_t Wl[2][192 * 72];

    const int t    = threadIdx.x;
    const int w    = t >> 6;
    const int lane = t & 63;
    const int g    = lane >> 4;
    const int col  = lane & 15;
    const int m0   = blockIdx.x * 64;

    const int xrow = t >> 2;        // 0..63
    const int xc   = (t & 3) * 16;  // 0,16,32,48

    float xf[16];
    uint4 wreg[6];

    auto LOADR = [&](int k0) {
        const float4* xp = reinterpret_cast<const float4*>(
            &X[(size_t)(m0 + xrow) * NC + k0 + xc]);
        #pragma unroll
        for (int j = 0; j < 4; ++j) {
            float4 v = xp[j];
            xf[4*j+0] = v.x; xf[4*j+1] = v.y; xf[4*j+2] = v.z; xf[4*j+3] = v.w;
        }
        #pragma unroll
        for (int i = 0; i < 6; ++i) {
            const int s = t + 256 * i;          // 0..1535
            const int n = s >> 3, part = s & 7;
            wreg[i] = *reinterpret_cast<const uint4*>(&WtG[n * NC + k0 + part * 8]);
        }
    };
    auto WRITES = [&](int b) {
        ushort_t xb[16];
        #pragma unroll
        for (int j = 0; j < 16; ++j) xb[j] = f2bf(xf[j]);
        *reinterpret_cast<uint4*>(&Xs[b][xrow * 72 + xc])     = reinterpret_cast<uint4*>(xb)[0];
        *reinterpret_cast<uint4*>(&Xs[b][xrow * 72 + xc + 8]) = reinterpret_cast<uint4*>(xb)[1];
        #pragma unroll
        for (int i = 0; i < 6; ++i) {
            const int s = t + 256 * i;
            const int n = s >> 3, part = s & 7;
            *reinterpret_cast<uint4*>(&Wl[b][n * 72 + part * 8]) = wreg[i];
        }
    };

    f32x4 acc[4][3];
    #pragma unroll
    for (int ri = 0; ri < 4; ++ri)
        #pragma unroll
        for (int tj = 0; tj < 3; ++tj) acc[ri][tj] = (f32x4){0.f, 0.f, 0.f, 0.f};

    LOADR(0);
    WRITES(0);

    for (int ks = 0; ks < 16; ++ks) {
        const int cur = ks & 1;
        if (ks < 15) LOADR((ks + 1) * 64);
        __syncthreads();
        const ushort_t* XsB = Xs[cur];
        const ushort_t* WlB = Wl[cur];
        #pragma unroll
        for (int c = 0; c < 2; ++c) {
            short8 af[4], bfr[3];
            #pragma unroll
            for (int ri = 0; ri < 4; ++ri)
                af[ri] = *reinterpret_cast<const short8*>(
                    &XsB[(16 * ri + col) * 72 + 32 * c + 8 * g]);
            #pragma unroll
            for (int tj = 0; tj < 3; ++tj)
                bfr[tj] = *reinterpret_cast<const short8*>(
                    &WlB[(48 * w + 16 * tj + col) * 72 + 32 * c + 8 * g]);
            #pragma unroll
            for (int ri = 0; ri < 4; ++ri)
                #pragma unroll
                for (int tj = 0; tj < 3; ++tj)
                    acc[ri][tj] = __builtin_amdgcn_mfma_f32_16x16x32_bf16(
                        af[ri], bfr[tj], acc[ri][tj], 0, 0, 0);
        }
        if (ks < 15) WRITES(cur ^ 1);
    }

    // epilogue: bias + bf16 store.  C/D: col=lane&15 (n), row=4g+r.
    #pragma unroll
    for (int tj = 0; tj < 3; ++tj) {
        const int ng    = 48 * w + 16 * tj + col;
        const int which = ng >> 6, ncol = ng & 63;
        const float* bp = (which == 0) ? bq : (which == 1) ? bk : bv;
        const float bb  = bp[ncol];
        ushort_t* Y = QKV + (size_t)which * BT * DK;
        #pragma unroll
        for (int ri = 0; ri < 4; ++ri)
            #pragma unroll
            for (int r = 0; r < 4; ++r) {
                const int rowg = m0 + 16 * ri + 4 * g + r;
                Y[(size_t)rowg * DK + ncol] = f2bf(acc[ri][tj][r] + bb);
            }
    }
}

// ---------------------------------------------------------------------------
// Kernel 2: causal flash attention on MFMA (unchanged from round 3, ~56us).
// ---------------------------------------------------------------------------
__global__ __launch_bounds__(256) void attn_mfma_kernel(
    const ushort_t* __restrict__ QKV, float* __restrict__ Out)
{
    const ushort_t* Qw = QKV;
    const ushort_t* Kw = QKV + (size_t)BT * DK;
    const ushort_t* Vw = QKV + (size_t)2 * BT * DK;

    __shared__ ushort_t Ks[2][64 * 72];
    __shared__ ushort_t Vt[2][64 * 72];
    __shared__ ushort_t Pl[4][16 * 72];

    const int t     = threadIdx.x;
    const int w     = t >> 6;
    const int lane  = t & 63;
    const int g     = lane >> 4;
    const int col   = lane & 15;
    const int batch = blockIdx.x & 7;
    const int qt    = 31 - (blockIdx.x >> 3);
    const int r0    = qt * 64;

    short8 qf[2];
    {
        const ushort_t* Qrow = Qw + ((size_t)(batch * NT) + r0 + w * 16 + col) * DK;
        qf[0] = *reinterpret_cast<const short8*>(Qrow + 8 * g);
        qf[1] = *reinterpret_cast<const short8*>(Qrow + 32 + 8 * g);
    }

    f32x4 Oa[4];
    #pragma unroll
    for (int dt = 0; dt < 4; ++dt) Oa[dt] = (f32x4){0.f, 0.f, 0.f, 0.f};
    float m[4] = {-INFINITY, -INFINITY, -INFINITY, -INFINITY};
    float l[4] = {0.f, 0.f, 0.f, 0.f};

    const int srow = t >> 2;
    const int seg  = t & 3;

    uint4 kreg[2], vreg[2];

    auto LOADR = [&](int kt) {
        const size_t go = ((size_t)(batch * NT) + kt * 64 + srow) * DK + seg * 16;
        const uint4* kp = reinterpret_cast<const uint4*>(Kw + go);
        kreg[0] = kp[0]; kreg[1] = kp[1];
        const uint4* vp = reinterpret_cast<const uint4*>(Vw + go);
        vreg[0] = vp[0]; vreg[1] = vp[1];
    };
    auto WRITES = [&](int b) {
        *reinterpret_cast<uint4*>(&Ks[b][srow * 72 + seg * 16])     = kreg[0];
        *reinterpret_cast<uint4*>(&Ks[b][srow * 72 + seg * 16 + 8]) = kreg[1];
        const uint_t* vr = reinterpret_cast<const uint_t*>(vreg);
        #pragma unroll
        for (int i = 0; i < 8; ++i) {
            const uint_t u = vr[i];
            Vt[b][(seg * 16 + 2 * i)     * 72 + srow] = (ushort_t)(u & 0xffffu);
            Vt[b][(seg * 16 + 2 * i + 1) * 72 + srow] = (ushort_t)(u >> 16);
        }
    };

    const int nkt = qt + 1;
    LOADR(0);
    WRITES(0);

    for (int kt = 0; kt < nkt; ++kt) {
        const int cur = kt & 1;
        if (kt + 1 < nkt) LOADR(kt + 1);
        __syncthreads();

        const ushort_t* KsB = Ks[cur];
        const ushort_t* VtB = Vt[cur];

        f32x4 sa[4];
        #pragma unroll
        for (int tj = 0; tj < 4; ++tj) sa[tj] = (f32x4){0.f, 0.f, 0.f, 0.f};
        #pragma unroll
        for (int tj = 0; tj < 4; ++tj) {
            const ushort_t* kb = &KsB[(col + 16 * tj) * 72 + 8 * g];
            short8 kf0 = *reinterpret_cast<const short8*>(kb);
            short8 kf1 = *reinterpret_cast<const short8*>(kb + 32);
            sa[tj] = __builtin_amdgcn_mfma_f32_16x16x32_bf16(qf[0], kf0, sa[tj], 0, 0, 0);
            sa[tj] = __builtin_amdgcn_mfma_f32_16x16x32_bf16(qf[1], kf1, sa[tj], 0, 0, 0);
        }

        float sv[4][4];
        #pragma unroll
        for (int tj = 0; tj < 4; ++tj)
            #pragma unroll
            for (int r = 0; r < 4; ++r) sv[tj][r] = sa[tj][r] * 0.125f;

        if (kt == qt) {
            const int rowb = r0 + 16 * w + 4 * g;
            const int s0   = kt * 64;
            #pragma unroll
            for (int tj = 0; tj < 4; ++tj) {
                const int key = s0 + col + 16 * tj;
                #pragma unroll
                for (int r = 0; r < 4; ++r)
                    if (key > rowb + r) sv[tj][r] = -INFINITY;
            }
        }

        float mt[4];
        #pragma unroll
        for (int r = 0; r < 4; ++r)
            mt[r] = fmaxf(fmaxf(sv[0][r], sv[1][r]), fmaxf(sv[2][r], sv[3][r]));
        #pragma unroll
        for (int off = 1; off < 16; off <<= 1)
            #pragma unroll
            for (int r = 0; r < 4; ++r)
                mt[r] = fmaxf(mt[r], __shfl_xor(mt[r], off, 16));

        float sc_old[4], lt[4], pb[4][4];
        #pragma unroll
        for (int r = 0; r < 4; ++r) {
            const float mn = fmaxf(m[r], mt[r]);
            sc_old[r] = __expf(m[r] - mn);
            m[r] = mn;
            lt[r] = 0.f;
        }
        #pragma unroll
        for (int tj = 0; tj < 4; ++tj)
            #pragma unroll
            for (int r = 0; r < 4; ++r) {
                pb[tj][r] = __expf(sv[tj][r] - m[r]);
                lt[r] += pb[tj][r];
            }
        #pragma unroll
        for (int off = 1; off < 16; off <<= 1)
            #pragma unroll
            for (int r = 0; r < 4; ++r) lt[r] += __shfl_xor(lt[r], off, 16);
        #pragma unroll
        for (int r = 0; r < 4; ++r) l[r] = l[r] * sc_old[r] + lt[r];
        #pragma unroll
        for (int dt = 0; dt < 4; ++dt)
            #pragma unroll
            for (int r = 0; r < 4; ++r) Oa[dt][r] *= sc_old[r];

        ushort_t* Pw = Pl[w];
        #pragma unroll
        for (int tj = 0; tj < 4; ++tj)
            #pragma unroll
            for (int r = 0; r < 4; ++r)
                Pw[(4 * g + r) * 72 + col + 16 * tj] = f2bf(pb[tj][r]);

        #pragma unroll
        for (int c = 0; c < 2; ++c) {
            short8 pf = *reinterpret_cast<const short8*>(&Pw[col * 72 + 32 * c + 8 * g]);
            #pragma unroll
            for (int dt = 0; dt < 4; ++dt) {
                short8 vf = *reinterpret_cast<const short8*>(
                    &VtB[(col + 16 * dt) * 72 + 32 * c + 8 * g]);
                Oa[dt] = __builtin_amdgcn_mfma_f32_16x16x32_bf16(pf, vf, Oa[dt], 0, 0, 0);
            }
        }

        if (kt + 1 < nkt) WRITES(cur ^ 1);
    }

    #pragma unroll
    for (int r = 0; r < 4; ++r) {
        const float inv = 1.0f / l[r];
        const int row = r0 + 16 * w + 4 * g + r;
        float* op = Out + ((size_t)(batch * NT) + row) * DK + col;
        #pragma unroll
        for (int dt = 0; dt < 4; ++dt) op[16 * dt] = Oa[dt][r] * inv;
    }
}

extern "C" void kernel_launch(void* const* d_in, const int* in_sizes, int n_in,
                              void* d_out, int out_size, void* d_ws, size_t ws_size,
                              hipStream_t stream) {
    const float* X  = (const float*)d_in[0];
    const float* Wq = (const float*)d_in[1];
    const float* bq = (const float*)d_in[2];
    const float* Wk = (const float*)d_in[3];
    const float* bk = (const float*)d_in[4];
    const float* Wv = (const float*)d_in[5];
    const float* bv = (const float*)d_in[6];
    float* Out = (float*)d_out;
    ushort_t* QKV = (ushort_t*)d_ws;     // Q | K | V, each BT*DK bf16 (6 MB)
    ushort_t* WtG = (ushort_t*)d_out;    // Wt[192][1024] bf16 scratch (393 KB),
                                         // consumed by proj, then overwritten by attn

    wt_prep_kernel<<<96, 256, 0, stream>>>(Wq, Wk, Wv, WtG);
    qkv_mfma_kernel<<<256, 256, 0, stream>>>(X, WtG, bq, bk, bv, QKV);
    attn_mfma_kernel<<<256, 256, 0, stream>>>(QKV, Out);
}

// Round 5
// 93.501 us; speedup vs baseline: 3.1108x; 1.1904x over previous
//
#include <hip/hip_runtime.h>
#include <math.h>

#define NB 8
#define NT 2048
#define NC 1024
#define DK 64
#define BT (NB*NT)

// ws layout: QKV bf16 (6,291,456 B) | attention partials (576 slots x 8704 B)
#define QKV_BYTES  (3u * BT * DK * 2u)
#define SLOT_BYTES 8704u   // Obf[64][64] bf16 (8192) + m f32[64] (256) + l f32[64] (256)

typedef unsigned short ushort_t;
typedef unsigned int uint_t;
typedef __attribute__((ext_vector_type(8))) short short8;
typedef __attribute__((ext_vector_type(4))) float f32x4;

__device__ __forceinline__ float bf2f(uint_t u) {
    union { uint_t i; float f; } v;
    v.i = u << 16;
    return v.f;
}
__device__ __forceinline__ ushort_t f2bf(float f) {
    union { float f; uint_t i; } v; v.f = f;
    uint_t x = v.i;
    return (ushort_t)((x + 0x7fffu + ((x >> 16) & 1u)) >> 16);
}

// prefix of segment slots for q-tiles [8, qt) within one batch (72 slots/batch)
__device__ __forceinline__ int seg_prefix(int qt) {
    return (qt < 16) ? (qt - 8) * 2
         : (qt < 24) ? 16 + (qt - 16) * 3
                     : 40 + (qt - 24) * 4;
}

// ---------------------------------------------------------------------------
// Kernel 0: W transpose+cast prep.  Wt[192][1024] bf16 in d_out scratch
// (393 KB; attn fully overwrites d_out afterwards).
// ---------------------------------------------------------------------------
__global__ __launch_bounds__(256) void wt_prep_kernel(
    const float* __restrict__ Wq, const float* __restrict__ Wk,
    const float* __restrict__ Wv, ushort_t* __restrict__ WtG)
{
    const int tg = blockIdx.x * 256 + threadIdx.x;   // 0..24575
    const int n  = tg >> 7;                          // 0..191
    const int k0 = (tg & 127) * 8;
    const float* W = (n < 64) ? Wq : (n < 128) ? Wk : Wv;
    const int nc = n & 63;
    ushort_t o[8];
    #pragma unroll
    for (int j = 0; j < 8; ++j) o[j] = f2bf(W[(size_t)(k0 + j) * DK + nc]);
    *reinterpret_cast<uint4*>(&WtG[n * NC + k0]) = *reinterpret_cast<uint4*>(o);
}

// ---------------------------------------------------------------------------
// Kernel 1: QKV projection on MFMA (unchanged from round 4, ~30us).
// ---------------------------------------------------------------------------
__global__ __launch_bounds__(256) void qkv_mfma_kernel(
    const float* __restrict__ X, const ushort_t* __restrict__ WtG,
    const float* __restrict__ bq, const float* __restrict__ bk,
    const float* __restrict__ bv, ushort_t* __restrict__ QKV)
{
    __shared__ ushort_t Xs[2][64 * 72];
    __shared__ ushort_t Wl[2][192 * 72];

    const int t    = threadIdx.x;
    const int w    = t >> 6;
    const int lane = t & 63;
    const int g    = lane >> 4;
    const int col  = lane & 15;
    const int m0   = blockIdx.x * 64;

    const int xrow = t >> 2;
    const int xc   = (t & 3) * 16;

    float xf[16];
    uint4 wreg[6];

    auto LOADR = [&](int k0) {
        const float4* xp = reinterpret_cast<const float4*>(
            &X[(size_t)(m0 + xrow) * NC + k0 + xc]);
        #pragma unroll
        for (int j = 0; j < 4; ++j) {
            float4 v = xp[j];
            xf[4*j+0] = v.x; xf[4*j+1] = v.y; xf[4*j+2] = v.z; xf[4*j+3] = v.w;
        }
        #pragma unroll
        for (int i = 0; i < 6; ++i) {
            const int s = t + 256 * i;
            const int n = s >> 3, part = s & 7;
            wreg[i] = *reinterpret_cast<const uint4*>(&WtG[n * NC + k0 + part * 8]);
        }
    };
    auto WRITES = [&](int b) {
        ushort_t xb[16];
        #pragma unroll
        for (int j = 0; j < 16; ++j) xb[j] = f2bf(xf[j]);
        *reinterpret_cast<uint4*>(&Xs[b][xrow * 72 + xc])     = reinterpret_cast<uint4*>(xb)[0];
        *reinterpret_cast<uint4*>(&Xs[b][xrow * 72 + xc + 8]) = reinterpret_cast<uint4*>(xb)[1];
        #pragma unroll
        for (int i = 0; i < 6; ++i) {
            const int s = t + 256 * i;
            const int n = s >> 3, part = s & 7;
            *reinterpret_cast<uint4*>(&Wl[b][n * 72 + part * 8]) = wreg[i];
        }
    };

    f32x4 acc[4][3];
    #pragma unroll
    for (int ri = 0; ri < 4; ++ri)
        #pragma unroll
        for (int tj = 0; tj < 3; ++tj) acc[ri][tj] = (f32x4){0.f, 0.f, 0.f, 0.f};

    LOADR(0);
    WRITES(0);

    for (int ks = 0; ks < 16; ++ks) {
        const int cur = ks & 1;
        if (ks < 15) LOADR((ks + 1) * 64);
        __syncthreads();
        const ushort_t* XsB = Xs[cur];
        const ushort_t* WlB = Wl[cur];
        #pragma unroll
        for (int c = 0; c < 2; ++c) {
            short8 af[4], bfr[3];
            #pragma unroll
            for (int ri = 0; ri < 4; ++ri)
                af[ri] = *reinterpret_cast<const short8*>(
                    &XsB[(16 * ri + col) * 72 + 32 * c + 8 * g]);
            #pragma unroll
            for (int tj = 0; tj < 3; ++tj)
                bfr[tj] = *reinterpret_cast<const short8*>(
                    &WlB[(48 * w + 16 * tj + col) * 72 + 32 * c + 8 * g]);
            #pragma unroll
            for (int ri = 0; ri < 4; ++ri)
                #pragma unroll
                for (int tj = 0; tj < 3; ++tj)
                    acc[ri][tj] = __builtin_amdgcn_mfma_f32_16x16x32_bf16(
                        af[ri], bfr[tj], acc[ri][tj], 0, 0, 0);
        }
        if (ks < 15) WRITES(cur ^ 1);
    }

    #pragma unroll
    for (int tj = 0; tj < 3; ++tj) {
        const int ng    = 48 * w + 16 * tj + col;
        const int which = ng >> 6, ncol = ng & 63;
        const float* bp = (which == 0) ? bq : (which == 1) ? bk : bv;
        const float bb  = bp[ncol];
        ushort_t* Y = QKV + (size_t)which * BT * DK;
        #pragma unroll
        for (int ri = 0; ri < 4; ++ri)
            #pragma unroll
            for (int r = 0; r < 4; ++r) {
                const int rowg = m0 + 16 * ri + 4 * g + r;
                Y[(size_t)rowg * DK + ncol] = f2bf(acc[ri][tj][r] + bb);
            }
    }
}

// ---------------------------------------------------------------------------
// Kernel 2: causal flash attention, k-split (flash-decoding style).
// Work item = (batch, qt of 64 rows, seg of <=8 k-tiles = 512 keys).
// Grid 640 = 8 batches x 80 items; 4 waves/block; ~all blocks co-resident
// (3 blocks/CU by LDS) -> 8-12 waves/CU vs round-4's 4.
// nseg==1 tiles write Out directly; else bf16 partial (O,m,l) to ws slot.
// ---------------------------------------------------------------------------
__global__ __launch_bounds__(256) void attn_seg_kernel(
    const ushort_t* __restrict__ QKV, float* __restrict__ Out,
    char* __restrict__ Pbase)
{
    const ushort_t* Qw = QKV;
    const ushort_t* Kw = QKV + (size_t)BT * DK;
    const ushort_t* Vw = QKV + (size_t)2 * BT * DK;

    __shared__ ushort_t Ks[2][64 * 72];
    __shared__ ushort_t Vt[2][64 * 72];
    __shared__ ushort_t Psh[4][16 * 72];

    const int t     = threadIdx.x;
    const int w     = t >> 6;
    const int lane  = t & 63;
    const int g     = lane >> 4;
    const int col   = lane & 15;
    const int batch = blockIdx.x & 7;
    const int item  = blockIdx.x >> 3;   // 0..79

    int qt, seg, nseg;
    if (item < 8)       { qt = item;                       seg = 0;            nseg = 1; }
    else if (item < 24) { int u = item - 8;  qt = 8  + (u >> 1); seg = u & 1;  nseg = 2; }
    else if (item < 48) { int u = item - 24; qt = 16 + u / 3;    seg = u % 3;  nseg = 3; }
    else                { int u = item - 48; qt = 24 + (u >> 2); seg = u & 3;  nseg = 4; }

    const int r0     = qt * 64;
    const int ktBeg  = seg * 8;
    const int ktEnd  = min(ktBeg + 8, qt + 1);

    short8 qf[2];
    {
        const ushort_t* Qrow = Qw + ((size_t)(batch * NT) + r0 + w * 16 + col) * DK;
        qf[0] = *reinterpret_cast<const short8*>(Qrow + 8 * g);
        qf[1] = *reinterpret_cast<const short8*>(Qrow + 32 + 8 * g);
    }

    f32x4 Oa[4];
    #pragma unroll
    for (int dt = 0; dt < 4; ++dt) Oa[dt] = (f32x4){0.f, 0.f, 0.f, 0.f};
    float m[4] = {-INFINITY, -INFINITY, -INFINITY, -INFINITY};
    float l[4] = {0.f, 0.f, 0.f, 0.f};

    const int srow = t >> 2;
    const int sseg = t & 3;

    uint4 kreg[2], vreg[2];

    auto LOADR = [&](int kt) {
        const size_t go = ((size_t)(batch * NT) + kt * 64 + srow) * DK + sseg * 16;
        const uint4* kp = reinterpret_cast<const uint4*>(Kw + go);
        kreg[0] = kp[0]; kreg[1] = kp[1];
        const uint4* vp = reinterpret_cast<const uint4*>(Vw + go);
        vreg[0] = vp[0]; vreg[1] = vp[1];
    };
    auto WRITES = [&](int b) {
        *reinterpret_cast<uint4*>(&Ks[b][srow * 72 + sseg * 16])     = kreg[0];
        *reinterpret_cast<uint4*>(&Ks[b][srow * 72 + sseg * 16 + 8]) = kreg[1];
        const uint_t* vr = reinterpret_cast<const uint_t*>(vreg);
        #pragma unroll
        for (int i = 0; i < 8; ++i) {
            const uint_t u = vr[i];
            Vt[b][(sseg * 16 + 2 * i)     * 72 + srow] = (ushort_t)(u & 0xffffu);
            Vt[b][(sseg * 16 + 2 * i + 1) * 72 + srow] = (ushort_t)(u >> 16);
        }
    };

    LOADR(ktBeg);
    WRITES(0);

    for (int kt = ktBeg; kt < ktEnd; ++kt) {
        const int cur = (kt - ktBeg) & 1;
        if (kt + 1 < ktEnd) LOADR(kt + 1);
        __syncthreads();

        const ushort_t* KsB = Ks[cur];
        const ushort_t* VtB = Vt[cur];

        f32x4 sa[4];
        #pragma unroll
        for (int tj = 0; tj < 4; ++tj) sa[tj] = (f32x4){0.f, 0.f, 0.f, 0.f};
        #pragma unroll
        for (int tj = 0; tj < 4; ++tj) {
            const ushort_t* kb = &KsB[(col + 16 * tj) * 72 + 8 * g];
            short8 kf0 = *reinterpret_cast<const short8*>(kb);
            short8 kf1 = *reinterpret_cast<const short8*>(kb + 32);
            sa[tj] = __builtin_amdgcn_mfma_f32_16x16x32_bf16(qf[0], kf0, sa[tj], 0, 0, 0);
            sa[tj] = __builtin_amdgcn_mfma_f32_16x16x32_bf16(qf[1], kf1, sa[tj], 0, 0, 0);
        }

        float sv[4][4];
        #pragma unroll
        for (int tj = 0; tj < 4; ++tj)
            #pragma unroll
            for (int r = 0; r < 4; ++r) sv[tj][r] = sa[tj][r] * 0.125f;

        if (kt == qt) {   // diagonal tile: causal mask (only ever in last segment)
            const int rowb = r0 + 16 * w + 4 * g;
            const int s0   = kt * 64;
            #pragma unroll
            for (int tj = 0; tj < 4; ++tj) {
                const int key = s0 + col + 16 * tj;
                #pragma unroll
                for (int r = 0; r < 4; ++r)
                    if (key > rowb + r) sv[tj][r] = -INFINITY;
            }
        }

        float mt[4];
        #pragma unroll
        for (int r = 0; r < 4; ++r)
            mt[r] = fmaxf(fmaxf(sv[0][r], sv[1][r]), fmaxf(sv[2][r], sv[3][r]));
        #pragma unroll
        for (int off = 1; off < 16; off <<= 1)
            #pragma unroll
            for (int r = 0; r < 4; ++r)
                mt[r] = fmaxf(mt[r], __shfl_xor(mt[r], off, 16));

        float sc_old[4], lt[4], pb[4][4];
        #pragma unroll
        for (int r = 0; r < 4; ++r) {
            const float mn = fmaxf(m[r], mt[r]);
            sc_old[r] = __expf(m[r] - mn);
            m[r] = mn;
            lt[r] = 0.f;
        }
        #pragma unroll
        for (int tj = 0; tj < 4; ++tj)
            #pragma unroll
            for (int r = 0; r < 4; ++r) {
                pb[tj][r] = __expf(sv[tj][r] - m[r]);
                lt[r] += pb[tj][r];
            }
        #pragma unroll
        for (int off = 1; off < 16; off <<= 1)
            #pragma unroll
            for (int r = 0; r < 4; ++r) lt[r] += __shfl_xor(lt[r], off, 16);
        #pragma unroll
        for (int r = 0; r < 4; ++r) l[r] = l[r] * sc_old[r] + lt[r];
        #pragma unroll
        for (int dt = 0; dt < 4; ++dt)
            #pragma unroll
            for (int r = 0; r < 4; ++r) Oa[dt][r] *= sc_old[r];

        ushort_t* Pw = Psh[w];
        #pragma unroll
        for (int tj = 0; tj < 4; ++tj)
            #pragma unroll
            for (int r = 0; r < 4; ++r)
                Pw[(4 * g + r) * 72 + col + 16 * tj] = f2bf(pb[tj][r]);

        #pragma unroll
        for (int c = 0; c < 2; ++c) {
            short8 pf = *reinterpret_cast<const short8*>(&Pw[col * 72 + 32 * c + 8 * g]);
            #pragma unroll
            for (int dt = 0; dt < 4; ++dt) {
                short8 vf = *reinterpret_cast<const short8*>(
                    &VtB[(col + 16 * dt) * 72 + 32 * c + 8 * g]);
                Oa[dt] = __builtin_amdgcn_mfma_f32_16x16x32_bf16(pf, vf, Oa[dt], 0, 0, 0);
            }
        }

        if (kt + 1 < ktEnd) WRITES(cur ^ 1);
    }

    if (nseg == 1) {
        #pragma unroll
        for (int r = 0; r < 4; ++r) {
            const float inv = 1.0f / l[r];
            const int row = r0 + 16 * w + 4 * g + r;
            float* op = Out + ((size_t)(batch * NT) + row) * DK + col;
            #pragma unroll
            for (int dt = 0; dt < 4; ++dt) op[16 * dt] = Oa[dt][r] * inv;
        }
    } else {
        const int slot = batch * 72 + seg_prefix(qt) + seg;
        char* sp = Pbase + (size_t)slot * SLOT_BYTES;
        ushort_t* Ob  = reinterpret_cast<ushort_t*>(sp);
        float*    Pm  = reinterpret_cast<float*>(sp + 8192);
        float*    Plv = reinterpret_cast<float*>(sp + 8448);
        #pragma unroll
        for (int r = 0; r < 4; ++r) {
            const int rloc = 16 * w + 4 * g + r;   // 0..63
            #pragma unroll
            for (int dt = 0; dt < 4; ++dt)
                Ob[rloc * 64 + 16 * dt + col] = f2bf(Oa[dt][r]);
            if (col == 0) { Pm[rloc] = m[r]; Plv[rloc] = l[r]; }
        }
    }
}

// ---------------------------------------------------------------------------
// Kernel 3: combine partial segments.  Grid 192 = 8 batches x 24 q-tiles
// (qt 8..31).  M = max m_s; O = sum e^{m_s-M} O_s; L = sum e^{m_s-M} l_s.
// ---------------------------------------------------------------------------
__global__ __launch_bounds__(256) void attn_combine_kernel(
    const char* __restrict__ Pbase, float* __restrict__ Out)
{
    const int bid   = blockIdx.x;       // 0..191
    const int batch = bid / 24;
    const int qt    = 8 + bid % 24;
    const int nseg  = (qt < 16) ? 2 : (qt < 24) ? 3 : 4;
    const int slot0 = batch * 72 + seg_prefix(qt);

    const int t   = threadIdx.x;
    const int row = t >> 2;
    const int d0  = (t & 3) * 16;

    float ms[4], ls[4];
    float M = -INFINITY;
    #pragma unroll
    for (int s = 0; s < 4; ++s)
        if (s < nseg) {
            const char* sp = Pbase + (size_t)(slot0 + s) * SLOT_BYTES;
            ms[s] = reinterpret_cast<const float*>(sp + 8192)[row];
            ls[s] = reinterpret_cast<const float*>(sp + 8448)[row];
            M = fmaxf(M, ms[s]);
        }

    float acc[16];
    #pragma unroll
    for (int j = 0; j < 16; ++j) acc[j] = 0.f;
    float ltot = 0.f;

    #pragma unroll
    for (int s = 0; s < 4; ++s)
        if (s < nseg) {
            const float wsc = __expf(ms[s] - M);
            ltot += wsc * ls[s];
            const ushort_t* Ob = reinterpret_cast<const ushort_t*>(
                Pbase + (size_t)(slot0 + s) * SLOT_BYTES) + row * 64 + d0;
            uint4 u0 = *reinterpret_cast<const uint4*>(Ob);
            uint4 u1 = *reinterpret_cast<const uint4*>(Ob + 8);
            const uint_t* uu = reinterpret_cast<const uint_t*>(&u0);
            #pragma unroll
            for (int j = 0; j < 4; ++j) {
                acc[2*j+0] += wsc * bf2f(uu[j] & 0xffffu);
                acc[2*j+1] += wsc * bf2f(uu[j] >> 16);
            }
            const uint_t* uv = reinterpret_cast<const uint_t*>(&u1);
            #pragma unroll
            for (int j = 0; j < 4; ++j) {
                acc[8+2*j+0] += wsc * bf2f(uv[j] & 0xffffu);
                acc[8+2*j+1] += wsc * bf2f(uv[j] >> 16);
            }
        }

    const float inv = 1.0f / ltot;
    float* op = Out + ((size_t)(batch * NT) + qt * 64 + row) * DK + d0;
    #pragma unroll
    for (int j = 0; j < 16; ++j) op[j] = acc[j] * inv;
}

extern "C" void kernel_launch(void* const* d_in, const int* in_sizes, int n_in,
                              void* d_out, int out_size, void* d_ws, size_t ws_size,
                              hipStream_t stream) {
    const float* X  = (const float*)d_in[0];
    const float* Wq = (const float*)d_in[1];
    const float* bq = (const float*)d_in[2];
    const float* Wk = (const float*)d_in[3];
    const float* bk = (const float*)d_in[4];
    const float* Wv = (const float*)d_in[5];
    const float* bv = (const float*)d_in[6];
    float* Out = (float*)d_out;
    ushort_t* QKV = (ushort_t*)d_ws;                 // 6 MB
    char* Pbase   = (char*)d_ws + QKV_BYTES;         // 576 slots x 8704 B (~4.8 MB)
    ushort_t* WtG = (ushort_t*)d_out;                // Wt scratch, overwritten by attn

    wt_prep_kernel<<<96, 256, 0, stream>>>(Wq, Wk, Wv, WtG);
    qkv_mfma_kernel<<<256, 256, 0, stream>>>(X, WtG, bq, bk, bv, QKV);
    attn_seg_kernel<<<640, 256, 0, stream>>>(QKV, Out, Pbase);
    attn_combine_kernel<<<192, 256, 0, stream>>>(Pbase, Out);
}

// Round 6
// 84.859 us; speedup vs baseline: 3.4276x; 1.1018x over previous
//
#include <hip/hip_runtime.h>
#include <math.h>

#define NB 8
#define NT 2048
#define NC 1024
#define DK 64
#define BT (NB*NT)

// ws layout: QKV bf16 (6,291,456 B) | attention partials (576 slots x 8704 B)
#define QKV_BYTES  (3u * BT * DK * 2u)
#define SLOT_BYTES 8704u   // Obf[64][64] bf16 (8192) + m f32[64] (256) + l f32[64] (256)

typedef unsigned short ushort_t;
typedef unsigned int uint_t;
typedef __attribute__((ext_vector_type(8))) short short8;
typedef __attribute__((ext_vector_type(4))) float f32x4;

__device__ __forceinline__ float bf2f(uint_t u) {
    union { uint_t i; float f; } v;
    v.i = u << 16;
    return v.f;
}
__device__ __forceinline__ ushort_t f2bf(float f) {
    union { float f; uint_t i; } v; v.f = f;
    uint_t x = v.i;
    return (ushort_t)((x + 0x7fffu + ((x >> 16) & 1u)) >> 16);
}

// prefix of segment slots for q-tiles [8, qt) within one batch (72 slots/batch)
__device__ __forceinline__ int seg_prefix(int qt) {
    return (qt < 16) ? (qt - 8) * 2
         : (qt < 24) ? 16 + (qt - 16) * 3
                     : 40 + (qt - 24) * 4;
}

// item table sorted by descending tile count (8-tile items first, then 7..1).
// entry = qt*4 + seg.  Longest-first dispatch -> no straggler tail.
__device__ __constant__ unsigned char g_item[80] = {
    // 8-tile (52 items)
    31*4+0,31*4+1,31*4+2,31*4+3,
    30*4+0,30*4+1,30*4+2,
    29*4+0,29*4+1,29*4+2,
    28*4+0,28*4+1,28*4+2,
    27*4+0,27*4+1,27*4+2,
    26*4+0,26*4+1,26*4+2,
    25*4+0,25*4+1,25*4+2,
    24*4+0,24*4+1,24*4+2,
    23*4+0,23*4+1,23*4+2,
    22*4+0,22*4+1,
    21*4+0,21*4+1,
    20*4+0,20*4+1,
    19*4+0,19*4+1,
    18*4+0,18*4+1,
    17*4+0,17*4+1,
    16*4+0,16*4+1,
    15*4+0,15*4+1,
    14*4+0, 13*4+0, 12*4+0, 11*4+0, 10*4+0, 9*4+0, 8*4+0,
    7*4+0,
    // 7-tile
    30*4+3, 22*4+2, 14*4+1, 6*4+0,
    // 6-tile
    29*4+3, 21*4+2, 13*4+1, 5*4+0,
    // 5-tile
    28*4+3, 20*4+2, 12*4+1, 4*4+0,
    // 4-tile
    27*4+3, 19*4+2, 11*4+1, 3*4+0,
    // 3-tile
    26*4+3, 18*4+2, 10*4+1, 2*4+0,
    // 2-tile
    25*4+3, 17*4+2, 9*4+1, 1*4+0,
    // 1-tile
    24*4+3, 16*4+2, 8*4+1, 0
};

// ---------------------------------------------------------------------------
// Kernel 0: W transpose+cast prep.  Wt[192][1024] bf16 in d_out scratch
// (393 KB; attn fully overwrites d_out afterwards).
// ---------------------------------------------------------------------------
__global__ __launch_bounds__(256) void wt_prep_kernel(
    const float* __restrict__ Wq, const float* __restrict__ Wk,
    const float* __restrict__ Wv, ushort_t* __restrict__ WtG)
{
    const int tg = blockIdx.x * 256 + threadIdx.x;   // 0..24575
    const int n  = tg >> 7;                          // 0..191
    const int k0 = (tg & 127) * 8;
    const float* W = (n < 64) ? Wq : (n < 128) ? Wk : Wv;
    const int nc = n & 63;
    ushort_t o[8];
    #pragma unroll
    for (int j = 0; j < 8; ++j) o[j] = f2bf(W[(size_t)(k0 + j) * DK + nc]);
    *reinterpret_cast<uint4*>(&WtG[n * NC + k0]) = *reinterpret_cast<uint4*>(o);
}

// ---------------------------------------------------------------------------
// Kernel 1: QKV projection on MFMA.
// Epilogue changes this round: Q pre-scaled by 0.125 (1/sqrt(dk));
// V written TRANSPOSED to global ([DK][BT] bf16) so attn stages it with
// vectorized conflict-free b128 writes (the scalar LDS transpose was the
// 3.2M-bank-conflict hot spot).
// ---------------------------------------------------------------------------
__global__ __launch_bounds__(256) void qkv_mfma_kernel(
    const float* __restrict__ X, const ushort_t* __restrict__ WtG,
    const float* __restrict__ bq, const float* __restrict__ bk,
    const float* __restrict__ bv, ushort_t* __restrict__ QKV)
{
    __shared__ ushort_t Xs[2][64 * 72];
    __shared__ ushort_t Wl[2][192 * 72];

    const int t    = threadIdx.x;
    const int w    = t >> 6;
    const int lane = t & 63;
    const int g    = lane >> 4;
    const int col  = lane & 15;
    const int m0   = blockIdx.x * 64;

    const int xrow = t >> 2;
    const int xc   = (t & 3) * 16;

    float xf[16];
    uint4 wreg[6];

    auto LOADR = [&](int k0) {
        const float4* xp = reinterpret_cast<const float4*>(
            &X[(size_t)(m0 + xrow) * NC + k0 + xc]);
        #pragma unroll
        for (int j = 0; j < 4; ++j) {
            float4 v = xp[j];
            xf[4*j+0] = v.x; xf[4*j+1] = v.y; xf[4*j+2] = v.z; xf[4*j+3] = v.w;
        }
        #pragma unroll
        for (int i = 0; i < 6; ++i) {
            const int s = t + 256 * i;
            const int n = s >> 3, part = s & 7;
            wreg[i] = *reinterpret_cast<const uint4*>(&WtG[n * NC + k0 + part * 8]);
        }
    };
    auto WRITES = [&](int b) {
        ushort_t xb[16];
        #pragma unroll
        for (int j = 0; j < 16; ++j) xb[j] = f2bf(xf[j]);
        *reinterpret_cast<uint4*>(&Xs[b][xrow * 72 + xc])     = reinterpret_cast<uint4*>(xb)[0];
        *reinterpret_cast<uint4*>(&Xs[b][xrow * 72 + xc + 8]) = reinterpret_cast<uint4*>(xb)[1];
        #pragma unroll
        for (int i = 0; i < 6; ++i) {
            const int s = t + 256 * i;
            const int n = s >> 3, part = s & 7;
            *reinterpret_cast<uint4*>(&Wl[b][n * 72 + part * 8]) = wreg[i];
        }
    };

    f32x4 acc[4][3];
    #pragma unroll
    for (int ri = 0; ri < 4; ++ri)
        #pragma unroll
        for (int tj = 0; tj < 3; ++tj) acc[ri][tj] = (f32x4){0.f, 0.f, 0.f, 0.f};

    LOADR(0);
    WRITES(0);

    for (int ks = 0; ks < 16; ++ks) {
        const int cur = ks & 1;
        if (ks < 15) LOADR((ks + 1) * 64);
        __syncthreads();
        const ushort_t* XsB = Xs[cur];
        const ushort_t* WlB = Wl[cur];
        #pragma unroll
        for (int c = 0; c < 2; ++c) {
            short8 af[4], bfr[3];
            #pragma unroll
            for (int ri = 0; ri < 4; ++ri)
                af[ri] = *reinterpret_cast<const short8*>(
                    &XsB[(16 * ri + col) * 72 + 32 * c + 8 * g]);
            #pragma unroll
            for (int tj = 0; tj < 3; ++tj)
                bfr[tj] = *reinterpret_cast<const short8*>(
                    &WlB[(48 * w + 16 * tj + col) * 72 + 32 * c + 8 * g]);
            #pragma unroll
            for (int ri = 0; ri < 4; ++ri)
                #pragma unroll
                for (int tj = 0; tj < 3; ++tj)
                    acc[ri][tj] = __builtin_amdgcn_mfma_f32_16x16x32_bf16(
                        af[ri], bfr[tj], acc[ri][tj], 0, 0, 0);
        }
        if (ks < 15) WRITES(cur ^ 1);
    }

    #pragma unroll
    for (int tj = 0; tj < 3; ++tj) {
        const int ng    = 48 * w + 16 * tj + col;
        const int which = ng >> 6, ncol = ng & 63;
        const float* bp = (which == 0) ? bq : (which == 1) ? bk : bv;
        const float bb  = bp[ncol];
        if (which == 2) {
            // V^T layout: Vt[d][global_t], d-major rows of length BT
            ushort_t* Vt = QKV + (size_t)2 * BT * DK;
            #pragma unroll
            for (int ri = 0; ri < 4; ++ri)
                #pragma unroll
                for (int r = 0; r < 4; ++r) {
                    const int rowg = m0 + 16 * ri + 4 * g + r;
                    Vt[(size_t)ncol * BT + rowg] = f2bf(acc[ri][tj][r] + bb);
                }
        } else {
            const float qs = (which == 0) ? 0.125f : 1.0f;   // fold 1/sqrt(dk) into Q
            ushort_t* Y = QKV + (size_t)which * BT * DK;
            #pragma unroll
            for (int ri = 0; ri < 4; ++ri)
                #pragma unroll
                for (int r = 0; r < 4; ++r) {
                    const int rowg = m0 + 16 * ri + 4 * g + r;
                    Y[(size_t)rowg * DK + ncol] = f2bf((acc[ri][tj][r] + bb) * qs);
                }
        }
    }
}

// ---------------------------------------------------------------------------
// Kernel 2: causal flash attention, k-split, V^T pre-transposed in global.
// Grid 640 = 8 batches x 80 items (longest-first table).  4 waves/block.
// All LDS staging is vectorized b128, conflict-free.
// ---------------------------------------------------------------------------
__global__ __launch_bounds__(256) void attn_seg_kernel(
    const ushort_t* __restrict__ QKV, float* __restrict__ Out,
    char* __restrict__ Pbase)
{
    const ushort_t* Qw = QKV;
    const ushort_t* Kw = QKV + (size_t)BT * DK;
    const ushort_t* Vw = QKV + (size_t)2 * BT * DK;   // [DK][BT]

    __shared__ ushort_t Ks[2][64 * 72];
    __shared__ ushort_t Vt[2][64 * 72];
    __shared__ ushort_t Psh[4][16 * 72];

    const int t     = threadIdx.x;
    const int w     = t >> 6;
    const int lane  = t & 63;
    const int g     = lane >> 4;
    const int col   = lane & 15;
    const int batch = blockIdx.x & 7;
    const int e     = g_item[blockIdx.x >> 3];
    const int qt    = e >> 2;
    const int seg   = e & 3;
    const int nseg  = (qt < 8) ? 1 : (qt < 16) ? 2 : (qt < 24) ? 3 : 4;

    const int r0     = qt * 64;
    const int ktBeg  = seg * 8;
    const int ktEnd  = min(ktBeg + 8, qt + 1);

    short8 qf[2];
    {
        const ushort_t* Qrow = Qw + ((size_t)(batch * NT) + r0 + w * 16 + col) * DK;
        qf[0] = *reinterpret_cast<const short8*>(Qrow + 8 * g);
        qf[1] = *reinterpret_cast<const short8*>(Qrow + 32 + 8 * g);
    }

    f32x4 Oa[4];
    #pragma unroll
    for (int dt = 0; dt < 4; ++dt) Oa[dt] = (f32x4){0.f, 0.f, 0.f, 0.f};
    float m[4] = {-INFINITY, -INFINITY, -INFINITY, -INFINITY};
    float l[4] = {0.f, 0.f, 0.f, 0.f};

    const int srow = t >> 2;
    const int sseg = t & 3;

    uint4 kreg[2], vreg[2];

    auto LOADR = [&](int kt) {
        const size_t gk = ((size_t)(batch * NT) + kt * 64 + srow) * DK + sseg * 16;
        const uint4* kp = reinterpret_cast<const uint4*>(Kw + gk);
        kreg[0] = kp[0]; kreg[1] = kp[1];
        // V^T: row srow = head dim d, cols = key positions
        const size_t gv = (size_t)srow * BT + (batch * NT + kt * 64) + sseg * 16;
        const uint4* vp = reinterpret_cast<const uint4*>(Vw + gv);
        vreg[0] = vp[0]; vreg[1] = vp[1];
    };
    auto WRITES = [&](int b) {
        *reinterpret_cast<uint4*>(&Ks[b][srow * 72 + sseg * 16])     = kreg[0];
        *reinterpret_cast<uint4*>(&Ks[b][srow * 72 + sseg * 16 + 8]) = kreg[1];
        *reinterpret_cast<uint4*>(&Vt[b][srow * 72 + sseg * 16])     = vreg[0];
        *reinterpret_cast<uint4*>(&Vt[b][srow * 72 + sseg * 16 + 8]) = vreg[1];
    };

    LOADR(ktBeg);
    WRITES(0);

    for (int kt = ktBeg; kt < ktEnd; ++kt) {
        const int cur = (kt - ktBeg) & 1;
        if (kt + 1 < ktEnd) LOADR(kt + 1);
        __syncthreads();

        const ushort_t* KsB = Ks[cur];
        const ushort_t* VtB = Vt[cur];

        f32x4 sa[4];
        #pragma unroll
        for (int tj = 0; tj < 4; ++tj) sa[tj] = (f32x4){0.f, 0.f, 0.f, 0.f};
        #pragma unroll
        for (int tj = 0; tj < 4; ++tj) {
            const ushort_t* kb = &KsB[(col + 16 * tj) * 72 + 8 * g];
            short8 kf0 = *reinterpret_cast<const short8*>(kb);
            short8 kf1 = *reinterpret_cast<const short8*>(kb + 32);
            sa[tj] = __builtin_amdgcn_mfma_f32_16x16x32_bf16(qf[0], kf0, sa[tj], 0, 0, 0);
            sa[tj] = __builtin_amdgcn_mfma_f32_16x16x32_bf16(qf[1], kf1, sa[tj], 0, 0, 0);
        }

        float sv[4][4];
        #pragma unroll
        for (int tj = 0; tj < 4; ++tj)
            #pragma unroll
            for (int r = 0; r < 4; ++r) sv[tj][r] = sa[tj][r];   // Q pre-scaled

        if (kt == qt) {   // diagonal tile: causal mask (only ever in last segment)
            const int rowb = r0 + 16 * w + 4 * g;
            const int s0   = kt * 64;
            #pragma unroll
            for (int tj = 0; tj < 4; ++tj) {
                const int key = s0 + col + 16 * tj;
                #pragma unroll
                for (int r = 0; r < 4; ++r)
                    if (key > rowb + r) sv[tj][r] = -INFINITY;
            }
        }

        float mt[4];
        #pragma unroll
        for (int r = 0; r < 4; ++r)
            mt[r] = fmaxf(fmaxf(sv[0][r], sv[1][r]), fmaxf(sv[2][r], sv[3][r]));
        #pragma unroll
        for (int off = 1; off < 16; off <<= 1)
            #pragma unroll
            for (int r = 0; r < 4; ++r)
                mt[r] = fmaxf(mt[r], __shfl_xor(mt[r], off, 16));

        float sc_old[4], lt[4], pb[4][4];
        #pragma unroll
        for (int r = 0; r < 4; ++r) {
            const float mn = fmaxf(m[r], mt[r]);
            sc_old[r] = __expf(m[r] - mn);
            m[r] = mn;
            lt[r] = 0.f;
        }
        #pragma unroll
        for (int tj = 0; tj < 4; ++tj)
            #pragma unroll
            for (int r = 0; r < 4; ++r) {
                pb[tj][r] = __expf(sv[tj][r] - m[r]);
                lt[r] += pb[tj][r];
            }
        #pragma unroll
        for (int off = 1; off < 16; off <<= 1)
            #pragma unroll
            for (int r = 0; r < 4; ++r) lt[r] += __shfl_xor(lt[r], off, 16);
        #pragma unroll
        for (int r = 0; r < 4; ++r) l[r] = l[r] * sc_old[r] + lt[r];
        #pragma unroll
        for (int dt = 0; dt < 4; ++dt)
            #pragma unroll
            for (int r = 0; r < 4; ++r) Oa[dt][r] *= sc_old[r];

        ushort_t* Pw = Psh[w];
        #pragma unroll
        for (int tj = 0; tj < 4; ++tj)
            #pragma unroll
            for (int r = 0; r < 4; ++r)
                Pw[(4 * g + r) * 72 + col + 16 * tj] = f2bf(pb[tj][r]);

        #pragma unroll
        for (int c = 0; c < 2; ++c) {
            short8 pf = *reinterpret_cast<const short8*>(&Pw[col * 72 + 32 * c + 8 * g]);
            #pragma unroll
            for (int dt = 0; dt < 4; ++dt) {
                short8 vf = *reinterpret_cast<const short8*>(
                    &VtB[(col + 16 * dt) * 72 + 32 * c + 8 * g]);
                Oa[dt] = __builtin_amdgcn_mfma_f32_16x16x32_bf16(pf, vf, Oa[dt], 0, 0, 0);
            }
        }

        if (kt + 1 < ktEnd) WRITES(cur ^ 1);
    }

    if (nseg == 1) {
        #pragma unroll
        for (int r = 0; r < 4; ++r) {
            const float inv = 1.0f / l[r];
            const int row = r0 + 16 * w + 4 * g + r;
            float* op = Out + ((size_t)(batch * NT) + row) * DK + col;
            #pragma unroll
            for (int dt = 0; dt < 4; ++dt) op[16 * dt] = Oa[dt][r] * inv;
        }
    } else {
        const int slot = batch * 72 + seg_prefix(qt) + seg;
        char* sp = Pbase + (size_t)slot * SLOT_BYTES;
        ushort_t* Ob  = reinterpret_cast<ushort_t*>(sp);
        float*    Pm  = reinterpret_cast<float*>(sp + 8192);
        float*    Plv = reinterpret_cast<float*>(sp + 8448);
        #pragma unroll
        for (int r = 0; r < 4; ++r) {
            const int rloc = 16 * w + 4 * g + r;   // 0..63
            #pragma unroll
            for (int dt = 0; dt < 4; ++dt)
                Ob[rloc * 64 + 16 * dt + col] = f2bf(Oa[dt][r]);
            if (col == 0) { Pm[rloc] = m[r]; Plv[rloc] = l[r]; }
        }
    }
}

// ---------------------------------------------------------------------------
// Kernel 3: combine partial segments.  Grid 192 = 8 batches x 24 q-tiles
// (qt 8..31).  M = max m_s; O = sum e^{m_s-M} O_s; L = sum e^{m_s-M} l_s.
// ---------------------------------------------------------------------------
__global__ __launch_bounds__(256) void attn_combine_kernel(
    const char* __restrict__ Pbase, float* __restrict__ Out)
{
    const int bid   = blockIdx.x;       // 0..191
    const int batch = bid / 24;
    const int qt    = 8 + bid % 24;
    const int nseg  = (qt < 16) ? 2 : (qt < 24) ? 3 : 4;
    const int slot0 = batch * 72 + seg_prefix(qt);

    const int t   = threadIdx.x;
    const int row = t >> 2;
    const int d0  = (t & 3) * 16;

    float ms[4], ls[4];
    float M = -INFINITY;
    #pragma unroll
    for (int s = 0; s < 4; ++s)
        if (s < nseg) {
            const char* sp = Pbase + (size_t)(slot0 + s) * SLOT_BYTES;
            ms[s] = reinterpret_cast<const float*>(sp + 8192)[row];
            ls[s] = reinterpret_cast<const float*>(sp + 8448)[row];
            M = fmaxf(M, ms[s]);
        }

    float acc[16];
    #pragma unroll
    for (int j = 0; j < 16; ++j) acc[j] = 0.f;
    float ltot = 0.f;

    #pragma unroll
    for (int s = 0; s < 4; ++s)
        if (s < nseg) {
            const float wsc = __expf(ms[s] - M);
            ltot += wsc * ls[s];
            const ushort_t* Ob = reinterpret_cast<const ushort_t*>(
                Pbase + (size_t)(slot0 + s) * SLOT_BYTES) + row * 64 + d0;
            uint4 u0 = *reinterpret_cast<const uint4*>(Ob);
            uint4 u1 = *reinterpret_cast<const uint4*>(Ob + 8);
            const uint_t* uu = reinterpret_cast<const uint_t*>(&u0);
            #pragma unroll
            for (int j = 0; j < 4; ++j) {
                acc[2*j+0] += wsc * bf2f(uu[j] & 0xffffu);
                acc[2*j+1] += wsc * bf2f(uu[j] >> 16);
            }
            const uint_t* uv = reinterpret_cast<const uint_t*>(&u1);
            #pragma unroll
            for (int j = 0; j < 4; ++j) {
                acc[8+2*j+0] += wsc * bf2f(uv[j] & 0xffffu);
                acc[8+2*j+1] += wsc * bf2f(uv[j] >> 16);
            }
        }

    const float inv = 1.0f / ltot;
    float* op = Out + ((size_t)(batch * NT) + qt * 64 + row) * DK + d0;
    #pragma unroll
    for (int j = 0; j < 16; ++j) op[j] = acc[j] * inv;
}

extern "C" void kernel_launch(void* const* d_in, const int* in_sizes, int n_in,
                              void* d_out, int out_size, void* d_ws, size_t ws_size,
                              hipStream_t stream) {
    const float* X  = (const float*)d_in[0];
    const float* Wq = (const float*)d_in[1];
    const float* bq = (const float*)d_in[2];
    const float* Wk = (const float*)d_in[3];
    const float* bk = (const float*)d_in[4];
    const float* Wv = (const float*)d_in[5];
    const float* bv = (const float*)d_in[6];
    float* Out = (float*)d_out;
    ushort_t* QKV = (ushort_t*)d_ws;                 // Q | K | V^T, each BT*DK bf16
    char* Pbase   = (char*)d_ws + QKV_BYTES;         // 576 slots x 8704 B (~4.8 MB)
    ushort_t* WtG = (ushort_t*)d_out;                // Wt scratch, overwritten by attn

    wt_prep_kernel<<<96, 256, 0, stream>>>(Wq, Wk, Wv, WtG);
    qkv_mfma_kernel<<<256, 256, 0, stream>>>(X, WtG, bq, bk, bv, QKV);
    attn_seg_kernel<<<640, 256, 0, stream>>>(QKV, Out, Pbase);
    attn_combine_kernel<<<192, 256, 0, stream>>>(Pbase, Out);
}

// Round 7
// 77.828 us; speedup vs baseline: 3.7372x; 1.0903x over previous
//
#include <hip/hip_runtime.h>
#include <math.h>

#define NB 8
#define NT 2048
#define NC 1024
#define DK 64
#define BT (NB*NT)

// ws layout: QKV bf16 (6,291,456 B) | attention partials (576 slots x 8704 B)
#define QKV_BYTES  (3u * BT * DK * 2u)
#define SLOT_BYTES 8704u   // Obf[64][64] bf16 (8192) + m f32[64] (256) + l f32[64] (256)

typedef unsigned short ushort_t;
typedef unsigned int uint_t;
typedef __attribute__((ext_vector_type(8))) short short8;
typedef __attribute__((ext_vector_type(4))) float f32x4;

__device__ __forceinline__ float bf2f(uint_t u) {
    union { uint_t i; float f; } v;
    v.i = u << 16;
    return v.f;
}
__device__ __forceinline__ ushort_t f2bf(float f) {
    union { float f; uint_t i; } v; v.f = f;
    uint_t x = v.i;
    return (ushort_t)((x + 0x7fffu + ((x >> 16) & 1u)) >> 16);
}

// prefix of segment slots for q-tiles [8, qt) within one batch (72 slots/batch)
__device__ __forceinline__ int seg_prefix(int qt) {
    return (qt < 16) ? (qt - 8) * 2
         : (qt < 24) ? 16 + (qt - 16) * 3
                     : 40 + (qt - 24) * 4;
}

// item table sorted by descending tile count (8-tile items first, then 7..1).
__device__ __constant__ unsigned char g_item[80] = {
    31*4+0,31*4+1,31*4+2,31*4+3,
    30*4+0,30*4+1,30*4+2,
    29*4+0,29*4+1,29*4+2,
    28*4+0,28*4+1,28*4+2,
    27*4+0,27*4+1,27*4+2,
    26*4+0,26*4+1,26*4+2,
    25*4+0,25*4+1,25*4+2,
    24*4+0,24*4+1,24*4+2,
    23*4+0,23*4+1,23*4+2,
    22*4+0,22*4+1,
    21*4+0,21*4+1,
    20*4+0,20*4+1,
    19*4+0,19*4+1,
    18*4+0,18*4+1,
    17*4+0,17*4+1,
    16*4+0,16*4+1,
    15*4+0,15*4+1,
    14*4+0, 13*4+0, 12*4+0, 11*4+0, 10*4+0, 9*4+0, 8*4+0,
    7*4+0,
    30*4+3, 22*4+2, 14*4+1, 6*4+0,
    29*4+3, 21*4+2, 13*4+1, 5*4+0,
    28*4+3, 20*4+2, 12*4+1, 4*4+0,
    27*4+3, 19*4+2, 11*4+1, 3*4+0,
    26*4+3, 18*4+2, 10*4+1, 2*4+0,
    25*4+3, 17*4+2, 9*4+1, 1*4+0,
    24*4+3, 16*4+2, 8*4+1, 0
};

// ---------------------------------------------------------------------------
// Kernel 0: W transpose+cast prep.  Wt[192][1024] bf16 in d_out scratch.
// ---------------------------------------------------------------------------
__global__ __launch_bounds__(256) void wt_prep_kernel(
    const float* __restrict__ Wq, const float* __restrict__ Wk,
    const float* __restrict__ Wv, ushort_t* __restrict__ WtG)
{
    const int tg = blockIdx.x * 256 + threadIdx.x;   // 0..24575
    const int n  = tg >> 7;                          // 0..191
    const int k0 = (tg & 127) * 8;
    const float* W = (n < 64) ? Wq : (n < 128) ? Wk : Wv;
    const int nc = n & 63;
    ushort_t o[8];
    #pragma unroll
    for (int j = 0; j < 8; ++j) o[j] = f2bf(W[(size_t)(k0 + j) * DK + nc]);
    *reinterpret_cast<uint4*>(&WtG[n * NC + k0]) = *reinterpret_cast<uint4*>(o);
}

// ---------------------------------------------------------------------------
// Kernel 1: QKV projection on MFMA — round-7 rewrite.
// M-tile 32, grid 512 (2 blocks/CU).  W read DIRECTLY from L2 into regs
// (double-buffered wA/wB, static indexing); only X staged in LDS (9 KB).
// V^T stored via LDS bounce -> coalesced 16B global stores (kills the 26MB
// write amplification of round 6's scalar scatter).  Q pre-scaled by 0.125.
// ---------------------------------------------------------------------------
__global__ __launch_bounds__(256, 2) void qkv_mfma_kernel(
    const float* __restrict__ X, const ushort_t* __restrict__ WtG,
    const float* __restrict__ bq, const float* __restrict__ bk,
    const float* __restrict__ bv, ushort_t* __restrict__ QKV)
{
    __shared__ ushort_t Xs[2][32 * 72];
    __shared__ ushort_t VtL[64 * 40];

    const int t    = threadIdx.x;
    const int w    = t >> 6;
    const int lane = t & 63;
    const int g    = lane >> 4;
    const int col  = lane & 15;
    const int m0   = blockIdx.x * 32;

    const int xrow = t >> 3;        // 0..31
    const int xc   = (t & 7) * 8;   // 0..56

    float xf[8];
    short8 wA[6], wB[6];

    auto LOADX = [&](int k0) {
        const float4* xp = reinterpret_cast<const float4*>(
            &X[(size_t)(m0 + xrow) * NC + k0 + xc]);
        float4 v0 = xp[0], v1 = xp[1];
        xf[0] = v0.x; xf[1] = v0.y; xf[2] = v0.z; xf[3] = v0.w;
        xf[4] = v1.x; xf[5] = v1.y; xf[6] = v1.z; xf[7] = v1.w;
    };
    auto LOADW = [&](int k0, short8* wn) {
        #pragma unroll
        for (int tj = 0; tj < 3; ++tj) {
            const int ng = 48 * w + 16 * tj + col;
            #pragma unroll
            for (int c = 0; c < 2; ++c)
                wn[tj * 2 + c] = *reinterpret_cast<const short8*>(
                    &WtG[ng * NC + k0 + 32 * c + 8 * g]);
        }
    };
    auto WRITEX = [&](int b) {
        ushort_t xb[8];
        #pragma unroll
        for (int j = 0; j < 8; ++j) xb[j] = f2bf(xf[j]);
        *reinterpret_cast<uint4*>(&Xs[b][xrow * 72 + xc]) =
            *reinterpret_cast<uint4*>(xb);
    };

    f32x4 acc[2][3];
    #pragma unroll
    for (int ri = 0; ri < 2; ++ri)
        #pragma unroll
        for (int tj = 0; tj < 3; ++tj) acc[ri][tj] = (f32x4){0.f, 0.f, 0.f, 0.f};

    auto COMPUTE = [&](int cur, short8* wc) {
        const ushort_t* XsB = Xs[cur];
        #pragma unroll
        for (int c = 0; c < 2; ++c) {
            short8 af[2];
            #pragma unroll
            for (int ri = 0; ri < 2; ++ri)
                af[ri] = *reinterpret_cast<const short8*>(
                    &XsB[(16 * ri + col) * 72 + 32 * c + 8 * g]);
            #pragma unroll
            for (int ri = 0; ri < 2; ++ri)
                #pragma unroll
                for (int tj = 0; tj < 3; ++tj)
                    acc[ri][tj] = __builtin_amdgcn_mfma_f32_16x16x32_bf16(
                        af[ri], wc[tj * 2 + c], acc[ri][tj], 0, 0, 0);
        }
    };

    LOADX(0);
    LOADW(0, wA);
    WRITEX(0);

    #pragma unroll
    for (int ks2 = 0; ks2 < 8; ++ks2) {
        {   // even step: buffer 0, compute wA, prefetch wB
            const int ks = 2 * ks2;
            if (ks < 15) { LOADX((ks + 1) * 64); LOADW((ks + 1) * 64, wB); }
            __syncthreads();
            COMPUTE(0, wA);
            if (ks < 15) WRITEX(1);
        }
        {   // odd step: buffer 1, compute wB, prefetch wA
            const int ks = 2 * ks2 + 1;
            if (ks < 15) { LOADX((ks + 1) * 64); LOADW((ks + 1) * 64, wA); }
            __syncthreads();
            COMPUTE(1, wB);
            if (ks < 15) WRITEX(0);
        }
    }

    // ---- epilogue ----
    #pragma unroll
    for (int tj = 0; tj < 3; ++tj) {
        const int ng    = 48 * w + 16 * tj + col;
        const int which = ng >> 6, ncol = ng & 63;
        const float* bp = (which == 0) ? bq : (which == 1) ? bk : bv;
        const float bb  = bp[ncol];
        if (which == 2) {
            // V: bounce through LDS for coalesced V^T stores
            #pragma unroll
            for (int ri = 0; ri < 2; ++ri)
                #pragma unroll
                for (int r = 0; r < 4; ++r)
                    VtL[ncol * 40 + 16 * ri + 4 * g + r] = f2bf(acc[ri][tj][r] + bb);
        } else {
            const float qs = (which == 0) ? 0.125f : 1.0f;   // fold 1/sqrt(dk) into Q
            ushort_t* Y = QKV + (size_t)which * BT * DK;
            #pragma unroll
            for (int ri = 0; ri < 2; ++ri)
                #pragma unroll
                for (int r = 0; r < 4; ++r) {
                    const int rowg = m0 + 16 * ri + 4 * g + r;
                    Y[(size_t)rowg * DK + ncol] = f2bf((acc[ri][tj][r] + bb) * qs);
                }
        }
    }
    __syncthreads();
    {   // coalesced V^T store: 64 d-rows x 32 t (64 B each)
        ushort_t* Vt = QKV + (size_t)2 * BT * DK;
        const int d   = t >> 2;
        const int sg  = t & 3;
        uint4 v = *reinterpret_cast<const uint4*>(&VtL[d * 40 + sg * 8]);
        *reinterpret_cast<uint4*>(&Vt[(size_t)d * BT + m0 + sg * 8]) = v;
    }
}

// ---------------------------------------------------------------------------
// Kernel 2: causal flash attention, k-split, V^T pre-transposed in global.
// (unchanged from round 6)
// ---------------------------------------------------------------------------
__global__ __launch_bounds__(256) void attn_seg_kernel(
    const ushort_t* __restrict__ QKV, float* __restrict__ Out,
    char* __restrict__ Pbase)
{
    const ushort_t* Qw = QKV;
    const ushort_t* Kw = QKV + (size_t)BT * DK;
    const ushort_t* Vw = QKV + (size_t)2 * BT * DK;   // [DK][BT]

    __shared__ ushort_t Ks[2][64 * 72];
    __shared__ ushort_t Vt[2][64 * 72];
    __shared__ ushort_t Psh[4][16 * 72];

    const int t     = threadIdx.x;
    const int w     = t >> 6;
    const int lane  = t & 63;
    const int g     = lane >> 4;
    const int col   = lane & 15;
    const int batch = blockIdx.x & 7;
    const int e     = g_item[blockIdx.x >> 3];
    const int qt    = e >> 2;
    const int seg   = e & 3;
    const int nseg  = (qt < 8) ? 1 : (qt < 16) ? 2 : (qt < 24) ? 3 : 4;

    const int r0     = qt * 64;
    const int ktBeg  = seg * 8;
    const int ktEnd  = min(ktBeg + 8, qt + 1);

    short8 qf[2];
    {
        const ushort_t* Qrow = Qw + ((size_t)(batch * NT) + r0 + w * 16 + col) * DK;
        qf[0] = *reinterpret_cast<const short8*>(Qrow + 8 * g);
        qf[1] = *reinterpret_cast<const short8*>(Qrow + 32 + 8 * g);
    }

    f32x4 Oa[4];
    #pragma unroll
    for (int dt = 0; dt < 4; ++dt) Oa[dt] = (f32x4){0.f, 0.f, 0.f, 0.f};
    float m[4] = {-INFINITY, -INFINITY, -INFINITY, -INFINITY};
    float l[4] = {0.f, 0.f, 0.f, 0.f};

    const int srow = t >> 2;
    const int sseg = t & 3;

    uint4 kreg[2], vreg[2];

    auto LOADR = [&](int kt) {
        const size_t gk = ((size_t)(batch * NT) + kt * 64 + srow) * DK + sseg * 16;
        const uint4* kp = reinterpret_cast<const uint4*>(Kw + gk);
        kreg[0] = kp[0]; kreg[1] = kp[1];
        const size_t gv = (size_t)srow * BT + (batch * NT + kt * 64) + sseg * 16;
        const uint4* vp = reinterpret_cast<const uint4*>(Vw + gv);
        vreg[0] = vp[0]; vreg[1] = vp[1];
    };
    auto WRITES = [&](int b) {
        *reinterpret_cast<uint4*>(&Ks[b][srow * 72 + sseg * 16])     = kreg[0];
        *reinterpret_cast<uint4*>(&Ks[b][srow * 72 + sseg * 16 + 8]) = kreg[1];
        *reinterpret_cast<uint4*>(&Vt[b][srow * 72 + sseg * 16])     = vreg[0];
        *reinterpret_cast<uint4*>(&Vt[b][srow * 72 + sseg * 16 + 8]) = vreg[1];
    };

    LOADR(ktBeg);
    WRITES(0);

    for (int kt = ktBeg; kt < ktEnd; ++kt) {
        const int cur = (kt - ktBeg) & 1;
        if (kt + 1 < ktEnd) LOADR(kt + 1);
        __syncthreads();

        const ushort_t* KsB = Ks[cur];
        const ushort_t* VtB = Vt[cur];

        f32x4 sa[4];
        #pragma unroll
        for (int tj = 0; tj < 4; ++tj) sa[tj] = (f32x4){0.f, 0.f, 0.f, 0.f};
        #pragma unroll
        for (int tj = 0; tj < 4; ++tj) {
            const ushort_t* kb = &KsB[(col + 16 * tj) * 72 + 8 * g];
            short8 kf0 = *reinterpret_cast<const short8*>(kb);
            short8 kf1 = *reinterpret_cast<const short8*>(kb + 32);
            sa[tj] = __builtin_amdgcn_mfma_f32_16x16x32_bf16(qf[0], kf0, sa[tj], 0, 0, 0);
            sa[tj] = __builtin_amdgcn_mfma_f32_16x16x32_bf16(qf[1], kf1, sa[tj], 0, 0, 0);
        }

        float sv[4][4];
        #pragma unroll
        for (int tj = 0; tj < 4; ++tj)
            #pragma unroll
            for (int r = 0; r < 4; ++r) sv[tj][r] = sa[tj][r];   // Q pre-scaled

        if (kt == qt) {
            const int rowb = r0 + 16 * w + 4 * g;
            const int s0   = kt * 64;
            #pragma unroll
            for (int tj = 0; tj < 4; ++tj) {
                const int key = s0 + col + 16 * tj;
                #pragma unroll
                for (int r = 0; r < 4; ++r)
                    if (key > rowb + r) sv[tj][r] = -INFINITY;
            }
        }

        float mt[4];
        #pragma unroll
        for (int r = 0; r < 4; ++r)
            mt[r] = fmaxf(fmaxf(sv[0][r], sv[1][r]), fmaxf(sv[2][r], sv[3][r]));
        #pragma unroll
        for (int off = 1; off < 16; off <<= 1)
            #pragma unroll
            for (int r = 0; r < 4; ++r)
                mt[r] = fmaxf(mt[r], __shfl_xor(mt[r], off, 16));

        float sc_old[4], lt[4], pb[4][4];
        #pragma unroll
        for (int r = 0; r < 4; ++r) {
            const float mn = fmaxf(m[r], mt[r]);
            sc_old[r] = __expf(m[r] - mn);
            m[r] = mn;
            lt[r] = 0.f;
        }
        #pragma unroll
        for (int tj = 0; tj < 4; ++tj)
            #pragma unroll
            for (int r = 0; r < 4; ++r) {
                pb[tj][r] = __expf(sv[tj][r] - m[r]);
                lt[r] += pb[tj][r];
            }
        #pragma unroll
        for (int off = 1; off < 16; off <<= 1)
            #pragma unroll
            for (int r = 0; r < 4; ++r) lt[r] += __shfl_xor(lt[r], off, 16);
        #pragma unroll
        for (int r = 0; r < 4; ++r) l[r] = l[r] * sc_old[r] + lt[r];
        #pragma unroll
        for (int dt = 0; dt < 4; ++dt)
            #pragma unroll
            for (int r = 0; r < 4; ++r) Oa[dt][r] *= sc_old[r];

        ushort_t* Pw = Psh[w];
        #pragma unroll
        for (int tj = 0; tj < 4; ++tj)
            #pragma unroll
            for (int r = 0; r < 4; ++r)
                Pw[(4 * g + r) * 72 + col + 16 * tj] = f2bf(pb[tj][r]);

        #pragma unroll
        for (int c = 0; c < 2; ++c) {
            short8 pf = *reinterpret_cast<const short8*>(&Pw[col * 72 + 32 * c + 8 * g]);
            #pragma unroll
            for (int dt = 0; dt < 4; ++dt) {
                short8 vf = *reinterpret_cast<const short8*>(
                    &VtB[(col + 16 * dt) * 72 + 32 * c + 8 * g]);
                Oa[dt] = __builtin_amdgcn_mfma_f32_16x16x32_bf16(pf, vf, Oa[dt], 0, 0, 0);
            }
        }

        if (kt + 1 < ktEnd) WRITES(cur ^ 1);
    }

    if (nseg == 1) {
        #pragma unroll
        for (int r = 0; r < 4; ++r) {
            const float inv = 1.0f / l[r];
            const int row = r0 + 16 * w + 4 * g + r;
            float* op = Out + ((size_t)(batch * NT) + row) * DK + col;
            #pragma unroll
            for (int dt = 0; dt < 4; ++dt) op[16 * dt] = Oa[dt][r] * inv;
        }
    } else {
        const int slot = batch * 72 + seg_prefix(qt) + seg;
        char* sp = Pbase + (size_t)slot * SLOT_BYTES;
        ushort_t* Ob  = reinterpret_cast<ushort_t*>(sp);
        float*    Pm  = reinterpret_cast<float*>(sp + 8192);
        float*    Plv = reinterpret_cast<float*>(sp + 8448);
        #pragma unroll
        for (int r = 0; r < 4; ++r) {
            const int rloc = 16 * w + 4 * g + r;   // 0..63
            #pragma unroll
            for (int dt = 0; dt < 4; ++dt)
                Ob[rloc * 64 + 16 * dt + col] = f2bf(Oa[dt][r]);
            if (col == 0) { Pm[rloc] = m[r]; Plv[rloc] = l[r]; }
        }
    }
}

// ---------------------------------------------------------------------------
// Kernel 3: combine partial segments (unchanged).
// ---------------------------------------------------------------------------
__global__ __launch_bounds__(256) void attn_combine_kernel(
    const char* __restrict__ Pbase, float* __restrict__ Out)
{
    const int bid   = blockIdx.x;       // 0..191
    const int batch = bid / 24;
    const int qt    = 8 + bid % 24;
    const int nseg  = (qt < 16) ? 2 : (qt < 24) ? 3 : 4;
    const int slot0 = batch * 72 + seg_prefix(qt);

    const int t   = threadIdx.x;
    const int row = t >> 2;
    const int d0  = (t & 3) * 16;

    float ms[4], ls[4];
    float M = -INFINITY;
    #pragma unroll
    for (int s = 0; s < 4; ++s)
        if (s < nseg) {
            const char* sp = Pbase + (size_t)(slot0 + s) * SLOT_BYTES;
            ms[s] = reinterpret_cast<const float*>(sp + 8192)[row];
            ls[s] = reinterpret_cast<const float*>(sp + 8448)[row];
            M = fmaxf(M, ms[s]);
        }

    float acc[16];
    #pragma unroll
    for (int j = 0; j < 16; ++j) acc[j] = 0.f;
    float ltot = 0.f;

    #pragma unroll
    for (int s = 0; s < 4; ++s)
        if (s < nseg) {
            const float wsc = __expf(ms[s] - M);
            ltot += wsc * ls[s];
            const ushort_t* Ob = reinterpret_cast<const ushort_t*>(
                Pbase + (size_t)(slot0 + s) * SLOT_BYTES) + row * 64 + d0;
            uint4 u0 = *reinterpret_cast<const uint4*>(Ob);
            uint4 u1 = *reinterpret_cast<const uint4*>(Ob + 8);
            const uint_t* uu = reinterpret_cast<const uint_t*>(&u0);
            #pragma unroll
            for (int j = 0; j < 4; ++j) {
                acc[2*j+0] += wsc * bf2f(uu[j] & 0xffffu);
                acc[2*j+1] += wsc * bf2f(uu[j] >> 16);
            }
            const uint_t* uv = reinterpret_cast<const uint_t*>(&u1);
            #pragma unroll
            for (int j = 0; j < 4; ++j) {
                acc[8+2*j+0] += wsc * bf2f(uv[j] & 0xffffu);
                acc[8+2*j+1] += wsc * bf2f(uv[j] >> 16);
            }
        }

    const float inv = 1.0f / ltot;
    float* op = Out + ((size_t)(batch * NT) + qt * 64 + row) * DK + d0;
    #pragma unroll
    for (int j = 0; j < 16; ++j) op[j] = acc[j] * inv;
}

extern "C" void kernel_launch(void* const* d_in, const int* in_sizes, int n_in,
                              void* d_out, int out_size, void* d_ws, size_t ws_size,
                              hipStream_t stream) {
    const float* X  = (const float*)d_in[0];
    const float* Wq = (const float*)d_in[1];
    const float* bq = (const float*)d_in[2];
    const float* Wk = (const float*)d_in[3];
    const float* bk = (const float*)d_in[4];
    const float* Wv = (const float*)d_in[5];
    const float* bv = (const float*)d_in[6];
    float* Out = (float*)d_out;
    ushort_t* QKV = (ushort_t*)d_ws;                 // Q | K | V^T, each BT*DK bf16
    char* Pbase   = (char*)d_ws + QKV_BYTES;         // 576 slots x 8704 B (~4.8 MB)
    ushort_t* WtG = (ushort_t*)d_out;                // Wt scratch, overwritten by attn

    wt_prep_kernel<<<96, 256, 0, stream>>>(Wq, Wk, Wv, WtG);
    qkv_mfma_kernel<<<512, 256, 0, stream>>>(X, WtG, bq, bk, bv, QKV);
    attn_seg_kernel<<<640, 256, 0, stream>>>(QKV, Out, Pbase);
    attn_combine_kernel<<<192, 256, 0, stream>>>(Pbase, Out);
}

// Round 8
// 67.858 us; speedup vs baseline: 4.2863x; 1.1469x over previous
//
#include <hip/hip_runtime.h>
#include <math.h>

#define NB 8
#define NT 2048
#define NC 1024
#define DK 64
#define BT (NB*NT)

// ws layout: QKV bf16 (6,291,456 B) | attention partials (576 slots x 8704 B)
#define QKV_BYTES  (3u * BT * DK * 2u)
#define SLOT_BYTES 8704u   // Obf[64][64] bf16 (8192) + m f32[64] (256) + l f32[64] (256)

typedef unsigned short ushort_t;
typedef unsigned int uint_t;
typedef __attribute__((ext_vector_type(8))) short short8;
typedef __attribute__((ext_vector_type(4))) float f32x4;

__device__ __forceinline__ float bf2f(uint_t u) {
    union { uint_t i; float f; } v;
    v.i = u << 16;
    return v.f;
}
__device__ __forceinline__ ushort_t f2bf(float f) {
    union { float f; uint_t i; } v; v.f = f;
    uint_t x = v.i;
    return (ushort_t)((x + 0x7fffu + ((x >> 16) & 1u)) >> 16);
}
__device__ __forceinline__ uint_t pack2bf(float lo, float hi) {
    return (uint_t)f2bf(lo) | ((uint_t)f2bf(hi) << 16);
}

// prefix of segment slots for q-tiles [8, qt) within one batch (72 slots/batch)
__device__ __forceinline__ int seg_prefix(int qt) {
    return (qt < 16) ? (qt - 8) * 2
         : (qt < 24) ? 16 + (qt - 16) * 3
                     : 40 + (qt - 24) * 4;
}

// item table sorted by descending tile count (8-tile items first, then 7..1).
__device__ __constant__ unsigned char g_item[80] = {
    31*4+0,31*4+1,31*4+2,31*4+3,
    30*4+0,30*4+1,30*4+2,
    29*4+0,29*4+1,29*4+2,
    28*4+0,28*4+1,28*4+2,
    27*4+0,27*4+1,27*4+2,
    26*4+0,26*4+1,26*4+2,
    25*4+0,25*4+1,25*4+2,
    24*4+0,24*4+1,24*4+2,
    23*4+0,23*4+1,23*4+2,
    22*4+0,22*4+1,
    21*4+0,21*4+1,
    20*4+0,20*4+1,
    19*4+0,19*4+1,
    18*4+0,18*4+1,
    17*4+0,17*4+1,
    16*4+0,16*4+1,
    15*4+0,15*4+1,
    14*4+0, 13*4+0, 12*4+0, 11*4+0, 10*4+0, 9*4+0, 8*4+0,
    7*4+0,
    30*4+3, 22*4+2, 14*4+1, 6*4+0,
    29*4+3, 21*4+2, 13*4+1, 5*4+0,
    28*4+3, 20*4+2, 12*4+1, 4*4+0,
    27*4+3, 19*4+2, 11*4+1, 3*4+0,
    26*4+3, 18*4+2, 10*4+1, 2*4+0,
    25*4+3, 17*4+2, 9*4+1, 1*4+0,
    24*4+3, 16*4+2, 8*4+1, 0
};

// ---------------------------------------------------------------------------
// Kernel 0: W transpose+cast prep.  Wt[192][1024] bf16 in d_out scratch.
// ---------------------------------------------------------------------------
__global__ __launch_bounds__(256) void wt_prep_kernel(
    const float* __restrict__ Wq, const float* __restrict__ Wk,
    const float* __restrict__ Wv, ushort_t* __restrict__ WtG)
{
    const int tg = blockIdx.x * 256 + threadIdx.x;   // 0..24575
    const int n  = tg >> 7;                          // 0..191
    const int k0 = (tg & 127) * 8;
    const float* W = (n < 64) ? Wq : (n < 128) ? Wk : Wv;
    const int nc = n & 63;
    ushort_t o[8];
    #pragma unroll
    for (int j = 0; j < 8; ++j) o[j] = f2bf(W[(size_t)(k0 + j) * DK + nc]);
    *reinterpret_cast<uint4*>(&WtG[n * NC + k0]) = *reinterpret_cast<uint4*>(o);
}

// ---------------------------------------------------------------------------
// Kernel 1: QKV projection on MFMA (unchanged from round 7).
// ---------------------------------------------------------------------------
__global__ __launch_bounds__(256, 2) void qkv_mfma_kernel(
    const float* __restrict__ X, const ushort_t* __restrict__ WtG,
    const float* __restrict__ bq, const float* __restrict__ bk,
    const float* __restrict__ bv, ushort_t* __restrict__ QKV)
{
    __shared__ ushort_t Xs[2][32 * 72];
    __shared__ ushort_t VtL[64 * 40];

    const int t    = threadIdx.x;
    const int w    = t >> 6;
    const int lane = t & 63;
    const int g    = lane >> 4;
    const int col  = lane & 15;
    const int m0   = blockIdx.x * 32;

    const int xrow = t >> 3;        // 0..31
    const int xc   = (t & 7) * 8;   // 0..56

    float xf[8];
    short8 wA[6], wB[6];

    auto LOADX = [&](int k0) {
        const float4* xp = reinterpret_cast<const float4*>(
            &X[(size_t)(m0 + xrow) * NC + k0 + xc]);
        float4 v0 = xp[0], v1 = xp[1];
        xf[0] = v0.x; xf[1] = v0.y; xf[2] = v0.z; xf[3] = v0.w;
        xf[4] = v1.x; xf[5] = v1.y; xf[6] = v1.z; xf[7] = v1.w;
    };
    auto LOADW = [&](int k0, short8* wn) {
        #pragma unroll
        for (int tj = 0; tj < 3; ++tj) {
            const int ng = 48 * w + 16 * tj + col;
            #pragma unroll
            for (int c = 0; c < 2; ++c)
                wn[tj * 2 + c] = *reinterpret_cast<const short8*>(
                    &WtG[ng * NC + k0 + 32 * c + 8 * g]);
        }
    };
    auto WRITEX = [&](int b) {
        ushort_t xb[8];
        #pragma unroll
        for (int j = 0; j < 8; ++j) xb[j] = f2bf(xf[j]);
        *reinterpret_cast<uint4*>(&Xs[b][xrow * 72 + xc]) =
            *reinterpret_cast<uint4*>(xb);
    };

    f32x4 acc[2][3];
    #pragma unroll
    for (int ri = 0; ri < 2; ++ri)
        #pragma unroll
        for (int tj = 0; tj < 3; ++tj) acc[ri][tj] = (f32x4){0.f, 0.f, 0.f, 0.f};

    auto COMPUTE = [&](int cur, short8* wc) {
        const ushort_t* XsB = Xs[cur];
        #pragma unroll
        for (int c = 0; c < 2; ++c) {
            short8 af[2];
            #pragma unroll
            for (int ri = 0; ri < 2; ++ri)
                af[ri] = *reinterpret_cast<const short8*>(
                    &XsB[(16 * ri + col) * 72 + 32 * c + 8 * g]);
            #pragma unroll
            for (int ri = 0; ri < 2; ++ri)
                #pragma unroll
                for (int tj = 0; tj < 3; ++tj)
                    acc[ri][tj] = __builtin_amdgcn_mfma_f32_16x16x32_bf16(
                        af[ri], wc[tj * 2 + c], acc[ri][tj], 0, 0, 0);
        }
    };

    LOADX(0);
    LOADW(0, wA);
    WRITEX(0);

    #pragma unroll
    for (int ks2 = 0; ks2 < 8; ++ks2) {
        {
            const int ks = 2 * ks2;
            if (ks < 15) { LOADX((ks + 1) * 64); LOADW((ks + 1) * 64, wB); }
            __syncthreads();
            COMPUTE(0, wA);
            if (ks < 15) WRITEX(1);
        }
        {
            const int ks = 2 * ks2 + 1;
            if (ks < 15) { LOADX((ks + 1) * 64); LOADW((ks + 1) * 64, wA); }
            __syncthreads();
            COMPUTE(1, wB);
            if (ks < 15) WRITEX(0);
        }
    }

    #pragma unroll
    for (int tj = 0; tj < 3; ++tj) {
        const int ng    = 48 * w + 16 * tj + col;
        const int which = ng >> 6, ncol = ng & 63;
        const float* bp = (which == 0) ? bq : (which == 1) ? bk : bv;
        const float bb  = bp[ncol];
        if (which == 2) {
            #pragma unroll
            for (int ri = 0; ri < 2; ++ri)
                #pragma unroll
                for (int r = 0; r < 4; ++r)
                    VtL[ncol * 40 + 16 * ri + 4 * g + r] = f2bf(acc[ri][tj][r] + bb);
        } else {
            const float qs = (which == 0) ? 0.125f : 1.0f;
            ushort_t* Y = QKV + (size_t)which * BT * DK;
            #pragma unroll
            for (int ri = 0; ri < 2; ++ri)
                #pragma unroll
                for (int r = 0; r < 4; ++r) {
                    const int rowg = m0 + 16 * ri + 4 * g + r;
                    Y[(size_t)rowg * DK + ncol] = f2bf((acc[ri][tj][r] + bb) * qs);
                }
        }
    }
    __syncthreads();
    {
        ushort_t* Vt = QKV + (size_t)2 * BT * DK;
        const int d   = t >> 2;
        const int sg  = t & 3;
        uint4 v = *reinterpret_cast<const uint4*>(&VtL[d * 40 + sg * 8]);
        *reinterpret_cast<uint4*>(&Vt[(size_t)d * BT + m0 + sg * 8]) = v;
    }
}

// ---------------------------------------------------------------------------
// Kernel 2: causal flash attention, k-split, SWAPPED QK^T (in-register P).
// sa = mfma(K,Q): D[key=4g+r+16tj][qrow=col].  Each lane owns ONE q-row:
// softmax reduce = local + 2 shfl_xor; P redistributed to PV A-fragments
// via 16 shfl + selects (no LDS round-trip).  LDS 36.9 KB -> 4 blocks/CU.
// ---------------------------------------------------------------------------
__global__ __launch_bounds__(256) void attn_seg_kernel(
    const ushort_t* __restrict__ QKV, float* __restrict__ Out,
    char* __restrict__ Pbase)
{
    const ushort_t* Qw = QKV;
    const ushort_t* Kw = QKV + (size_t)BT * DK;
    const ushort_t* Vw = QKV + (size_t)2 * BT * DK;   // [DK][BT]

    __shared__ ushort_t Ks[2][64 * 72];
    __shared__ ushort_t Vt[2][64 * 72];

    const int t     = threadIdx.x;
    const int w     = t >> 6;
    const int lane  = t & 63;
    const int g     = lane >> 4;
    const int col   = lane & 15;
    const int batch = blockIdx.x & 7;
    const int e     = g_item[blockIdx.x >> 3];
    const int qt    = e >> 2;
    const int seg   = e & 3;
    const int nseg  = (qt < 8) ? 1 : (qt < 16) ? 2 : (qt < 24) ? 3 : 4;

    const int r0     = qt * 64;
    const int qrow   = r0 + 16 * w + col;   // the q-row THIS LANE owns
    const int ktBeg  = seg * 8;
    const int ktEnd  = min(ktBeg + 8, qt + 1);

    short8 qf[2];
    {
        const ushort_t* Qrow = Qw + ((size_t)(batch * NT) + qrow) * DK;
        qf[0] = *reinterpret_cast<const short8*>(Qrow + 8 * g);
        qf[1] = *reinterpret_cast<const short8*>(Qrow + 32 + 8 * g);
    }

    f32x4 Oa[4];
    #pragma unroll
    for (int dt = 0; dt < 4; ++dt) Oa[dt] = (f32x4){0.f, 0.f, 0.f, 0.f};
    float m = -INFINITY, l = 0.0f;

    const int srow = t >> 2;
    const int sseg = t & 3;

    uint4 kreg[2], vreg[2];

    auto LOADR = [&](int kt) {
        const size_t gk = ((size_t)(batch * NT) + kt * 64 + srow) * DK + sseg * 16;
        const uint4* kp = reinterpret_cast<const uint4*>(Kw + gk);
        kreg[0] = kp[0]; kreg[1] = kp[1];
        const size_t gv = (size_t)srow * BT + (batch * NT + kt * 64) + sseg * 16;
        const uint4* vp = reinterpret_cast<const uint4*>(Vw + gv);
        vreg[0] = vp[0]; vreg[1] = vp[1];
    };
    auto WRITES = [&](int b) {
        *reinterpret_cast<uint4*>(&Ks[b][srow * 72 + sseg * 16])     = kreg[0];
        *reinterpret_cast<uint4*>(&Ks[b][srow * 72 + sseg * 16 + 8]) = kreg[1];
        *reinterpret_cast<uint4*>(&Vt[b][srow * 72 + sseg * 16])     = vreg[0];
        *reinterpret_cast<uint4*>(&Vt[b][srow * 72 + sseg * 16 + 8]) = vreg[1];
    };

    LOADR(ktBeg);
    WRITES(0);

    for (int kt = ktBeg; kt < ktEnd; ++kt) {
        const int cur = (kt - ktBeg) & 1;
        if (kt + 1 < ktEnd) LOADR(kt + 1);
        __syncthreads();

        const ushort_t* KsB = Ks[cur];
        const ushort_t* VtB = Vt[cur];

        // ---- QK^T swapped: sa[tj] = K_tile(tj) . Q  -> S^T ----
        f32x4 sa[4];
        #pragma unroll
        for (int tj = 0; tj < 4; ++tj) sa[tj] = (f32x4){0.f, 0.f, 0.f, 0.f};
        #pragma unroll
        for (int tj = 0; tj < 4; ++tj) {
            const ushort_t* kb = &KsB[(col + 16 * tj) * 72 + 8 * g];
            short8 kf0 = *reinterpret_cast<const short8*>(kb);
            short8 kf1 = *reinterpret_cast<const short8*>(kb + 32);
            sa[tj] = __builtin_amdgcn_mfma_f32_16x16x32_bf16(kf0, qf[0], sa[tj], 0, 0, 0);
            sa[tj] = __builtin_amdgcn_mfma_f32_16x16x32_bf16(kf1, qf[1], sa[tj], 0, 0, 0);
        }
        // lane holds S[key = s0+16tj+4g+r][qrow=col]  (Q pre-scaled by 1/8)

        float sv[4][4];
        #pragma unroll
        for (int tj = 0; tj < 4; ++tj)
            #pragma unroll
            for (int r = 0; r < 4; ++r) sv[tj][r] = sa[tj][r];

        if (kt == qt) {   // diagonal tile: causal mask
            const int s0 = kt * 64;
            #pragma unroll
            for (int tj = 0; tj < 4; ++tj)
                #pragma unroll
                for (int r = 0; r < 4; ++r)
                    if (s0 + 16 * tj + 4 * g + r > qrow) sv[tj][r] = -INFINITY;
        }

        // ---- online softmax: per-lane row, 2-step cross-lane reduce ----
        float vmax = sv[0][0];
        #pragma unroll
        for (int tj = 0; tj < 4; ++tj)
            #pragma unroll
            for (int r = 0; r < 4; ++r) vmax = fmaxf(vmax, sv[tj][r]);
        vmax = fmaxf(vmax, __shfl_xor(vmax, 16, 64));
        vmax = fmaxf(vmax, __shfl_xor(vmax, 32, 64));

        const float mn = fmaxf(m, vmax);
        const float sc = __expf(m - mn);
        m = mn;

        float p[4][4];
        float lt = 0.f;
        #pragma unroll
        for (int tj = 0; tj < 4; ++tj)
            #pragma unroll
            for (int r = 0; r < 4; ++r) {
                p[tj][r] = __expf(sv[tj][r] - mn);
                lt += p[tj][r];
            }
        lt += __shfl_xor(lt, 16, 64);
        lt += __shfl_xor(lt, 32, 64);
        l = l * sc + lt;

        // O rescale: O rows are 4g+r; fetch their sc from lane 20g+r (col=4g+r)
        float sco[4];
        #pragma unroll
        for (int r = 0; r < 4; ++r) sco[r] = __shfl(sc, 20 * g + r, 64);
        #pragma unroll
        for (int dt = 0; dt < 4; ++dt)
            #pragma unroll
            for (int r = 0; r < 4; ++r) Oa[dt][r] *= sco[r];

        // ---- pack P -> bf16 pairs, redistribute to PV A-fragments ----
        uint_t pk0[4], pk1[4];
        #pragma unroll
        for (int tj = 0; tj < 4; ++tj) {
            pk0[tj] = pack2bf(p[tj][0], p[tj][1]);
            pk1[tj] = pack2bf(p[tj][2], p[tj][3]);
        }
        const int sA = col + 32 * (g & 1);   // src lane (low half of frag)
        const int sB = sA + 16;              // src lane (high half)
        const bool hi = (g >= 2);            // tile select: 2c+(g>>1)

        #pragma unroll
        for (int c = 0; c < 2; ++c) {
            uint_t w0a = __shfl(pk0[2*c], sA, 64), w0b = __shfl(pk0[2*c+1], sA, 64);
            uint_t w1a = __shfl(pk1[2*c], sA, 64), w1b = __shfl(pk1[2*c+1], sA, 64);
            uint_t w2a = __shfl(pk0[2*c], sB, 64), w2b = __shfl(pk0[2*c+1], sB, 64);
            uint_t w3a = __shfl(pk1[2*c], sB, 64), w3b = __shfl(pk1[2*c+1], sB, 64);
            uint_t pa[4];
            pa[0] = hi ? w0b : w0a;
            pa[1] = hi ? w1b : w1a;
            pa[2] = hi ? w2b : w2a;
            pa[3] = hi ? w3b : w3a;
            short8 paf = *reinterpret_cast<const short8*>(pa);
            #pragma unroll
            for (int dt = 0; dt < 4; ++dt) {
                short8 vf = *reinterpret_cast<const short8*>(
                    &VtB[(col + 16 * dt) * 72 + 32 * c + 8 * g]);
                Oa[dt] = __builtin_amdgcn_mfma_f32_16x16x32_bf16(paf, vf, Oa[dt], 0, 0, 0);
            }
        }

        if (kt + 1 < ktEnd) WRITES(cur ^ 1);
    }

    // ---- epilogue: O rows are 4g+r; fetch l (and m) from lane 20g+r ----
    float lr[4];
    #pragma unroll
    for (int r = 0; r < 4; ++r) lr[r] = __shfl(l, 20 * g + r, 64);

    if (nseg == 1) {
        #pragma unroll
        for (int r = 0; r < 4; ++r) {
            const float inv = 1.0f / lr[r];
            const int row = r0 + 16 * w + 4 * g + r;
            float* op = Out + ((size_t)(batch * NT) + row) * DK + col;
            #pragma unroll
            for (int dt = 0; dt < 4; ++dt) op[16 * dt] = Oa[dt][r] * inv;
        }
    } else {
        float mr[4];
        #pragma unroll
        for (int r = 0; r < 4; ++r) mr[r] = __shfl(m, 20 * g + r, 64);
        const int slot = batch * 72 + seg_prefix(qt) + seg;
        char* sp = Pbase + (size_t)slot * SLOT_BYTES;
        ushort_t* Ob  = reinterpret_cast<ushort_t*>(sp);
        float*    Pm  = reinterpret_cast<float*>(sp + 8192);
        float*    Plv = reinterpret_cast<float*>(sp + 8448);
        #pragma unroll
        for (int r = 0; r < 4; ++r) {
            const int rloc = 16 * w + 4 * g + r;   // 0..63
            #pragma unroll
            for (int dt = 0; dt < 4; ++dt)
                Ob[rloc * 64 + 16 * dt + col] = f2bf(Oa[dt][r]);
            if (col == 0) { Pm[rloc] = mr[r]; Plv[rloc] = lr[r]; }
        }
    }
}

// ---------------------------------------------------------------------------
// Kernel 3: combine partial segments (unchanged).
// ---------------------------------------------------------------------------
__global__ __launch_bounds__(256) void attn_combine_kernel(
    const char* __restrict__ Pbase, float* __restrict__ Out)
{
    const int bid   = blockIdx.x;       // 0..191
    const int batch = bid / 24;
    const int qt    = 8 + bid % 24;
    const int nseg  = (qt < 16) ? 2 : (qt < 24) ? 3 : 4;
    const int slot0 = batch * 72 + seg_prefix(qt);

    const int t   = threadIdx.x;
    const int row = t >> 2;
    const int d0  = (t & 3) * 16;

    float ms[4], ls[4];
    float M = -INFINITY;
    #pragma unroll
    for (int s = 0; s < 4; ++s)
        if (s < nseg) {
            const char* sp = Pbase + (size_t)(slot0 + s) * SLOT_BYTES;
            ms[s] = reinterpret_cast<const float*>(sp + 8192)[row];
            ls[s] = reinterpret_cast<const float*>(sp + 8448)[row];
            M = fmaxf(M, ms[s]);
        }

    float acc[16];
    #pragma unroll
    for (int j = 0; j < 16; ++j) acc[j] = 0.f;
    float ltot = 0.f;

    #pragma unroll
    for (int s = 0; s < 4; ++s)
        if (s < nseg) {
            const float wsc = __expf(ms[s] - M);
            ltot += wsc * ls[s];
            const ushort_t* Ob = reinterpret_cast<const ushort_t*>(
                Pbase + (size_t)(slot0 + s) * SLOT_BYTES) + row * 64 + d0;
            uint4 u0 = *reinterpret_cast<const uint4*>(Ob);
            uint4 u1 = *reinterpret_cast<const uint4*>(Ob + 8);
            const uint_t* uu = reinterpret_cast<const uint_t*>(&u0);
            #pragma unroll
            for (int j = 0; j < 4; ++j) {
                acc[2*j+0] += wsc * bf2f(uu[j] & 0xffffu);
                acc[2*j+1] += wsc * bf2f(uu[j] >> 16);
            }
            const uint_t* uv = reinterpret_cast<const uint_t*>(&u1);
            #pragma unroll
            for (int j = 0; j < 4; ++j) {
                acc[8+2*j+0] += wsc * bf2f(uv[j] & 0xffffu);
                acc[8+2*j+1] += wsc * bf2f(uv[j] >> 16);
            }
        }

    const float inv = 1.0f / ltot;
    float* op = Out + ((size_t)(batch * NT) + qt * 64 + row) * DK + d0;
    #pragma unroll
    for (int j = 0; j < 16; ++j) op[j] = acc[j] * inv;
}

extern "C" void kernel_launch(void* const* d_in, const int* in_sizes, int n_in,
                              void* d_out, int out_size, void* d_ws, size_t ws_size,
                              hipStream_t stream) {
    const float* X  = (const float*)d_in[0];
    const float* Wq = (const float*)d_in[1];
    const float* bq = (const float*)d_in[2];
    const float* Wk = (const float*)d_in[3];
    const float* bk = (const float*)d_in[4];
    const float* Wv = (const float*)d_in[5];
    const float* bv = (const float*)d_in[6];
    float* Out = (float*)d_out;
    ushort_t* QKV = (ushort_t*)d_ws;                 // Q | K | V^T, each BT*DK bf16
    char* Pbase   = (char*)d_ws + QKV_BYTES;         // 576 slots x 8704 B (~4.8 MB)
    ushort_t* WtG = (ushort_t*)d_out;                // Wt scratch, overwritten by attn

    wt_prep_kernel<<<96, 256, 0, stream>>>(Wq, Wk, Wv, WtG);
    qkv_mfma_kernel<<<512, 256, 0, stream>>>(X, WtG, bq, bk, bv, QKV);
    attn_seg_kernel<<<640, 256, 0, stream>>>(QKV, Out, Pbase);
    attn_combine_kernel<<<192, 256, 0, stream>>>(Pbase, Out);
}

// Round 9
// 66.043 us; speedup vs baseline: 4.4041x; 1.0275x over previous
//
#include <hip/hip_runtime.h>
#include <math.h>

#define NB 8
#define NT 2048
#define NC 1024
#define DK 64
#define BT (NB*NT)

// ws layout: QKV bf16 (6,291,456 B) | attention partials (1120 slots x 8704 B)
#define QKV_BYTES  (3u * BT * DK * 2u)
#define SLOT_BYTES 8704u   // Obf[64][64] bf16 (8192) + m f32[64] (256) + l f32[64] (256)

typedef unsigned short ushort_t;
typedef unsigned int uint_t;
typedef __attribute__((ext_vector_type(8))) short short8;
typedef __attribute__((ext_vector_type(4))) float f32x4;

__device__ __forceinline__ float bf2f(uint_t u) {
    union { uint_t i; float f; } v;
    v.i = u << 16;
    return v.f;
}
__device__ __forceinline__ ushort_t f2bf(float f) {
    union { float f; uint_t i; } v; v.f = f;
    uint_t x = v.i;
    return (ushort_t)((x + 0x7fffu + ((x >> 16) & 1u)) >> 16);
}
__device__ __forceinline__ uint_t pack2bf(float lo, float hi) {
    return (uint_t)f2bf(lo) | ((uint_t)f2bf(hi) << 16);
}

// slot prefix within a batch for q-tile qt (qt>=4): sum of nseg over q'=4..qt-1,
// nseg(q') = q'/4 + 1.  140 slots per batch total.
__device__ __forceinline__ int seg_prefix(int qt) {
    const int a = qt >> 2;
    return 2 * a * (a + 1) - 4 + (qt & 3) * (a + 1);
}

// ---------------------------------------------------------------------------
// Kernel 0: W transpose+cast prep.  Wt[192][1024] bf16 in d_out scratch.
// ---------------------------------------------------------------------------
__global__ __launch_bounds__(256) void wt_prep_kernel(
    const float* __restrict__ Wq, const float* __restrict__ Wk,
    const float* __restrict__ Wv, ushort_t* __restrict__ WtG)
{
    const int tg = blockIdx.x * 256 + threadIdx.x;   // 0..24575
    const int n  = tg >> 7;                          // 0..191
    const int k0 = (tg & 127) * 8;
    const float* W = (n < 64) ? Wq : (n < 128) ? Wk : Wv;
    const int nc = n & 63;
    ushort_t o[8];
    #pragma unroll
    for (int j = 0; j < 8; ++j) o[j] = f2bf(W[(size_t)(k0 + j) * DK + nc]);
    *reinterpret_cast<uint4*>(&WtG[n * NC + k0]) = *reinterpret_cast<uint4*>(o);
}

// ---------------------------------------------------------------------------
// Kernel 1: QKV projection on MFMA (unchanged from round 7).
// ---------------------------------------------------------------------------
__global__ __launch_bounds__(256, 2) void qkv_mfma_kernel(
    const float* __restrict__ X, const ushort_t* __restrict__ WtG,
    const float* __restrict__ bq, const float* __restrict__ bk,
    const float* __restrict__ bv, ushort_t* __restrict__ QKV)
{
    __shared__ ushort_t Xs[2][32 * 72];
    __shared__ ushort_t VtL[64 * 40];

    const int t    = threadIdx.x;
    const int w    = t >> 6;
    const int lane = t & 63;
    const int g    = lane >> 4;
    const int col  = lane & 15;
    const int m0   = blockIdx.x * 32;

    const int xrow = t >> 3;        // 0..31
    const int xc   = (t & 7) * 8;   // 0..56

    float xf[8];
    short8 wA[6], wB[6];

    auto LOADX = [&](int k0) {
        const float4* xp = reinterpret_cast<const float4*>(
            &X[(size_t)(m0 + xrow) * NC + k0 + xc]);
        float4 v0 = xp[0], v1 = xp[1];
        xf[0] = v0.x; xf[1] = v0.y; xf[2] = v0.z; xf[3] = v0.w;
        xf[4] = v1.x; xf[5] = v1.y; xf[6] = v1.z; xf[7] = v1.w;
    };
    auto LOADW = [&](int k0, short8* wn) {
        #pragma unroll
        for (int tj = 0; tj < 3; ++tj) {
            const int ng = 48 * w + 16 * tj + col;
            #pragma unroll
            for (int c = 0; c < 2; ++c)
                wn[tj * 2 + c] = *reinterpret_cast<const short8*>(
                    &WtG[ng * NC + k0 + 32 * c + 8 * g]);
        }
    };
    auto WRITEX = [&](int b) {
        ushort_t xb[8];
        #pragma unroll
        for (int j = 0; j < 8; ++j) xb[j] = f2bf(xf[j]);
        *reinterpret_cast<uint4*>(&Xs[b][xrow * 72 + xc]) =
            *reinterpret_cast<uint4*>(xb);
    };

    f32x4 acc[2][3];
    #pragma unroll
    for (int ri = 0; ri < 2; ++ri)
        #pragma unroll
        for (int tj = 0; tj < 3; ++tj) acc[ri][tj] = (f32x4){0.f, 0.f, 0.f, 0.f};

    auto COMPUTE = [&](int cur, short8* wc) {
        const ushort_t* XsB = Xs[cur];
        #pragma unroll
        for (int c = 0; c < 2; ++c) {
            short8 af[2];
            #pragma unroll
            for (int ri = 0; ri < 2; ++ri)
                af[ri] = *reinterpret_cast<const short8*>(
                    &XsB[(16 * ri + col) * 72 + 32 * c + 8 * g]);
            #pragma unroll
            for (int ri = 0; ri < 2; ++ri)
                #pragma unroll
                for (int tj = 0; tj < 3; ++tj)
                    acc[ri][tj] = __builtin_amdgcn_mfma_f32_16x16x32_bf16(
                        af[ri], wc[tj * 2 + c], acc[ri][tj], 0, 0, 0);
        }
    };

    LOADX(0);
    LOADW(0, wA);
    WRITEX(0);

    #pragma unroll
    for (int ks2 = 0; ks2 < 8; ++ks2) {
        {
            const int ks = 2 * ks2;
            if (ks < 15) { LOADX((ks + 1) * 64); LOADW((ks + 1) * 64, wB); }
            __syncthreads();
            COMPUTE(0, wA);
            if (ks < 15) WRITEX(1);
        }
        {
            const int ks = 2 * ks2 + 1;
            if (ks < 15) { LOADX((ks + 1) * 64); LOADW((ks + 1) * 64, wA); }
            __syncthreads();
            COMPUTE(1, wB);
            if (ks < 15) WRITEX(0);
        }
    }

    #pragma unroll
    for (int tj = 0; tj < 3; ++tj) {
        const int ng    = 48 * w + 16 * tj + col;
        const int which = ng >> 6, ncol = ng & 63;
        const float* bp = (which == 0) ? bq : (which == 1) ? bk : bv;
        const float bb  = bp[ncol];
        if (which == 2) {
            #pragma unroll
            for (int ri = 0; ri < 2; ++ri)
                #pragma unroll
                for (int r = 0; r < 4; ++r)
                    VtL[ncol * 40 + 16 * ri + 4 * g + r] = f2bf(acc[ri][tj][r] + bb);
        } else {
            const float qs = (which == 0) ? 0.125f : 1.0f;
            ushort_t* Y = QKV + (size_t)which * BT * DK;
            #pragma unroll
            for (int ri = 0; ri < 2; ++ri)
                #pragma unroll
                for (int r = 0; r < 4; ++r) {
                    const int rowg = m0 + 16 * ri + 4 * g + r;
                    Y[(size_t)rowg * DK + ncol] = f2bf((acc[ri][tj][r] + bb) * qs);
                }
        }
    }
    __syncthreads();
    {
        ushort_t* Vt = QKV + (size_t)2 * BT * DK;
        const int d   = t >> 2;
        const int sg  = t & 3;
        uint4 v = *reinterpret_cast<const uint4*>(&VtL[d * 40 + sg * 8]);
        *reinterpret_cast<uint4*>(&Vt[(size_t)d * BT + m0 + sg * 8]) = v;
    }
}

// ---------------------------------------------------------------------------
// Kernel 2: causal flash attention — k-segment-resident, ZERO barriers in
// the hot loop.  Block = (batch, k-seg s of 256 keys, chunk of 2 q-tiles).
// Stage K[256][72] + V^T[64][288] (72 KB) once, one barrier, then loop
// q-tiles x k-tiles: pure MFMA + in-register softmax (swapped QK^T) + L2 Q
// reads.  Partial (O,m,l) per (qt, seg) to ws; qt<4 writes Out direct.
// Grid 576 = 8 batches x 72 chunks.
// ---------------------------------------------------------------------------
__global__ __launch_bounds__(256) void attn_seg_kernel(
    const ushort_t* __restrict__ QKV, float* __restrict__ Out,
    char* __restrict__ Pbase)
{
    const ushort_t* Qw = QKV;
    const ushort_t* Kw = QKV + (size_t)BT * DK;
    const ushort_t* Vw = QKV + (size_t)2 * BT * DK;   // [DK][BT]

    __shared__ ushort_t Ks[256 * 72];    // 256 key-rows x 64 dk (stride 72)
    __shared__ ushort_t VtL[64 * 288];   // 64 d-rows x 256 keys (4 tiles x 72)

    const int t     = threadIdx.x;
    const int w     = t >> 6;
    const int lane  = t & 63;
    const int g     = lane >> 4;
    const int col   = lane & 15;
    const int batch = blockIdx.x & 7;
    const int u     = blockIdx.x >> 3;   // 0..71

    // decode (s, chunk): seg s covers q-tiles 4s..31, chunked in pairs.
    int s;
    if      (u < 16) s = 0;
    else if (u < 30) s = 1;
    else if (u < 42) s = 2;
    else if (u < 52) s = 3;
    else if (u < 60) s = 4;
    else if (u < 66) s = 5;
    else if (u < 70) s = 6;
    else             s = 7;
    const int off2 = 16 * s - s * (s - 1);
    const int qt0  = 4 * s + 2 * (u - off2);
    const int kbase = 256 * s;

    // ---- stage the whole 256-key segment (once) ----
    {
        const int sr = t >> 2;       // 0..63
        const int ss = t & 3;        // 16-ushort segment
        #pragma unroll
        for (int i = 0; i < 4; ++i) {
            const int krow = 64 * i + sr;
            const size_t gk = ((size_t)(batch * NT) + kbase + krow) * DK + ss * 16;
            const uint4* kp = reinterpret_cast<const uint4*>(Kw + gk);
            *reinterpret_cast<uint4*>(&Ks[krow * 72 + ss * 16])     = kp[0];
            *reinterpret_cast<uint4*>(&Ks[krow * 72 + ss * 16 + 8]) = kp[1];
            const size_t gv = (size_t)sr * BT + (batch * NT + kbase + 64 * i) + ss * 16;
            const uint4* vp = reinterpret_cast<const uint4*>(Vw + gv);
            *reinterpret_cast<uint4*>(&VtL[sr * 288 + 72 * i + ss * 16])     = vp[0];
            *reinterpret_cast<uint4*>(&VtL[sr * 288 + 72 * i + ss * 16 + 8]) = vp[1];
        }
    }
    __syncthreads();   // the ONLY barrier

    #pragma unroll
    for (int iq = 0; iq < 2; ++iq) {
        const int qt   = qt0 + iq;
        const int qrow = qt * 64 + 16 * w + col;   // q-row THIS LANE owns
        const int kcnt = min(4, qt - 4 * s + 1);   // k-tiles in this segment
        const int diag = qt - 4 * s;               // local index of diagonal tile

        short8 qf0, qf1;
        {
            const ushort_t* Qrow = Qw + ((size_t)(batch * NT) + qrow) * DK;
            qf0 = *reinterpret_cast<const short8*>(Qrow + 8 * g);
            qf1 = *reinterpret_cast<const short8*>(Qrow + 32 + 8 * g);
        }

        f32x4 Oa[4];
        #pragma unroll
        for (int dt = 0; dt < 4; ++dt) Oa[dt] = (f32x4){0.f, 0.f, 0.f, 0.f};
        float m = -INFINITY, l = 0.0f;

        for (int ktl = 0; ktl < kcnt; ++ktl) {
            // ---- QK^T swapped: lane holds S[key][qrow=col] ----
            f32x4 sa[4];
            #pragma unroll
            for (int tj = 0; tj < 4; ++tj) sa[tj] = (f32x4){0.f, 0.f, 0.f, 0.f};
            #pragma unroll
            for (int tj = 0; tj < 4; ++tj) {
                const ushort_t* kb = &Ks[(64 * ktl + col + 16 * tj) * 72 + 8 * g];
                short8 kf0 = *reinterpret_cast<const short8*>(kb);
                short8 kf1 = *reinterpret_cast<const short8*>(kb + 32);
                sa[tj] = __builtin_amdgcn_mfma_f32_16x16x32_bf16(kf0, qf0, sa[tj], 0, 0, 0);
                sa[tj] = __builtin_amdgcn_mfma_f32_16x16x32_bf16(kf1, qf1, sa[tj], 0, 0, 0);
            }

            float sv[4][4];
            #pragma unroll
            for (int tj = 0; tj < 4; ++tj)
                #pragma unroll
                for (int r = 0; r < 4; ++r) sv[tj][r] = sa[tj][r];

            if (ktl == diag) {   // diagonal tile: causal mask
                const int s0 = (kbase + 64 * ktl);
                #pragma unroll
                for (int tj = 0; tj < 4; ++tj)
                    #pragma unroll
                    for (int r = 0; r < 4; ++r)
                        if (s0 + 16 * tj + 4 * g + r > qrow) sv[tj][r] = -INFINITY;
            }

            // ---- online softmax: per-lane row, 2 shfl reduce ----
            float vmax = sv[0][0];
            #pragma unroll
            for (int tj = 0; tj < 4; ++tj)
                #pragma unroll
                for (int r = 0; r < 4; ++r) vmax = fmaxf(vmax, sv[tj][r]);
            vmax = fmaxf(vmax, __shfl_xor(vmax, 16, 64));
            vmax = fmaxf(vmax, __shfl_xor(vmax, 32, 64));

            const float mn = fmaxf(m, vmax);
            const float sc = __expf(m - mn);
            m = mn;

            float p[4][4];
            float lt = 0.f;
            #pragma unroll
            for (int tj = 0; tj < 4; ++tj)
                #pragma unroll
                for (int r = 0; r < 4; ++r) {
                    p[tj][r] = __expf(sv[tj][r] - mn);
                    lt += p[tj][r];
                }
            lt += __shfl_xor(lt, 16, 64);
            lt += __shfl_xor(lt, 32, 64);
            l = l * sc + lt;

            float sco[4];
            #pragma unroll
            for (int r = 0; r < 4; ++r) sco[r] = __shfl(sc, 20 * g + r, 64);
            #pragma unroll
            for (int dt = 0; dt < 4; ++dt)
                #pragma unroll
                for (int r = 0; r < 4; ++r) Oa[dt][r] *= sco[r];

            // ---- pack P -> bf16, redistribute to PV A-fragments ----
            uint_t pk0[4], pk1[4];
            #pragma unroll
            for (int tj = 0; tj < 4; ++tj) {
                pk0[tj] = pack2bf(p[tj][0], p[tj][1]);
                pk1[tj] = pack2bf(p[tj][2], p[tj][3]);
            }
            const int sA = col + 32 * (g & 1);
            const int sB = sA + 16;
            const bool hi = (g >= 2);

            #pragma unroll
            for (int c = 0; c < 2; ++c) {
                uint_t w0a = __shfl(pk0[2*c], sA, 64), w0b = __shfl(pk0[2*c+1], sA, 64);
                uint_t w1a = __shfl(pk1[2*c], sA, 64), w1b = __shfl(pk1[2*c+1], sA, 64);
                uint_t w2a = __shfl(pk0[2*c], sB, 64), w2b = __shfl(pk0[2*c+1], sB, 64);
                uint_t w3a = __shfl(pk1[2*c], sB, 64), w3b = __shfl(pk1[2*c+1], sB, 64);
                uint_t pa[4];
                pa[0] = hi ? w0b : w0a;
                pa[1] = hi ? w1b : w1a;
                pa[2] = hi ? w2b : w2a;
                pa[3] = hi ? w3b : w3a;
                short8 paf = *reinterpret_cast<const short8*>(pa);
                #pragma unroll
                for (int dt = 0; dt < 4; ++dt) {
                    short8 vf = *reinterpret_cast<const short8*>(
                        &VtL[(col + 16 * dt) * 288 + 72 * ktl + 32 * c + 8 * g]);
                    Oa[dt] = __builtin_amdgcn_mfma_f32_16x16x32_bf16(paf, vf, Oa[dt], 0, 0, 0);
                }
            }
        }

        // ---- epilogue for this q-tile ----
        float lr[4];
        #pragma unroll
        for (int r = 0; r < 4; ++r) lr[r] = __shfl(l, 20 * g + r, 64);

        if (qt < 4) {   // single segment: write Out directly
            #pragma unroll
            for (int r = 0; r < 4; ++r) {
                const float inv = 1.0f / lr[r];
                const int row = qt * 64 + 16 * w + 4 * g + r;
                float* op = Out + ((size_t)(batch * NT) + row) * DK + col;
                #pragma unroll
                for (int dt = 0; dt < 4; ++dt) op[16 * dt] = Oa[dt][r] * inv;
            }
        } else {
            float mr[4];
            #pragma unroll
            for (int r = 0; r < 4; ++r) mr[r] = __shfl(m, 20 * g + r, 64);
            const int slot = batch * 140 + seg_prefix(qt) + s;
            char* sp = Pbase + (size_t)slot * SLOT_BYTES;
            ushort_t* Ob  = reinterpret_cast<ushort_t*>(sp);
            float*    Pm  = reinterpret_cast<float*>(sp + 8192);
            float*    Plv = reinterpret_cast<float*>(sp + 8448);
            #pragma unroll
            for (int r = 0; r < 4; ++r) {
                const int rloc = 16 * w + 4 * g + r;   // 0..63
                #pragma unroll
                for (int dt = 0; dt < 4; ++dt)
                    Ob[rloc * 64 + 16 * dt + col] = f2bf(Oa[dt][r]);
                if (col == 0) { Pm[rloc] = mr[r]; Plv[rloc] = lr[r]; }
            }
        }
    }
}

// ---------------------------------------------------------------------------
// Kernel 3: combine partial segments.  Grid 224 = 8 batches x 28 q-tiles
// (qt 4..31), up to 8 segments each.
// ---------------------------------------------------------------------------
__global__ __launch_bounds__(256) void attn_combine_kernel(
    const char* __restrict__ Pbase, float* __restrict__ Out)
{
    const int bid   = blockIdx.x;       // 0..223
    const int batch = bid / 28;
    const int qt    = 4 + bid % 28;
    const int nseg  = (qt >> 2) + 1;    // 2..8
    const int slot0 = batch * 140 + seg_prefix(qt);

    const int t   = threadIdx.x;
    const int row = t >> 2;
    const int d0  = (t & 3) * 16;

    float ms[8], ls[8];
    float M = -INFINITY;
    #pragma unroll
    for (int s = 0; s < 8; ++s)
        if (s < nseg) {
            const char* sp = Pbase + (size_t)(slot0 + s) * SLOT_BYTES;
            ms[s] = reinterpret_cast<const float*>(sp + 8192)[row];
            ls[s] = reinterpret_cast<const float*>(sp + 8448)[row];
            M = fmaxf(M, ms[s]);
        }

    float acc[16];
    #pragma unroll
    for (int j = 0; j < 16; ++j) acc[j] = 0.f;
    float ltot = 0.f;

    #pragma unroll
    for (int s = 0; s < 8; ++s)
        if (s < nseg) {
            const float wsc = __expf(ms[s] - M);
            ltot += wsc * ls[s];
            const ushort_t* Ob = reinterpret_cast<const ushort_t*>(
                Pbase + (size_t)(slot0 + s) * SLOT_BYTES) + row * 64 + d0;
            uint4 u0 = *reinterpret_cast<const uint4*>(Ob);
            uint4 u1 = *reinterpret_cast<const uint4*>(Ob + 8);
            const uint_t* uu = reinterpret_cast<const uint_t*>(&u0);
            #pragma unroll
            for (int j = 0; j < 4; ++j) {
                acc[2*j+0] += wsc * bf2f(uu[j] & 0xffffu);
                acc[2*j+1] += wsc * bf2f(uu[j] >> 16);
            }
            const uint_t* uv = reinterpret_cast<const uint_t*>(&u1);
            #pragma unroll
            for (int j = 0; j < 4; ++j) {
                acc[8+2*j+0] += wsc * bf2f(uv[j] & 0xffffu);
                acc[8+2*j+1] += wsc * bf2f(uv[j] >> 16);
            }
        }

    const float inv = 1.0f / ltot;
    float* op = Out + ((size_t)(batch * NT) + qt * 64 + row) * DK + d0;
    #pragma unroll
    for (int j = 0; j < 16; ++j) op[j] = acc[j] * inv;
}

extern "C" void kernel_launch(void* const* d_in, const int* in_sizes, int n_in,
                              void* d_out, int out_size, void* d_ws, size_t ws_size,
                              hipStream_t stream) {
    const float* X  = (const float*)d_in[0];
    const float* Wq = (const float*)d_in[1];
    const float* bq = (const float*)d_in[2];
    const float* Wk = (const float*)d_in[3];
    const float* bk = (const float*)d_in[4];
    const float* Wv = (const float*)d_in[5];
    const float* bv = (const float*)d_in[6];
    float* Out = (float*)d_out;
    ushort_t* QKV = (ushort_t*)d_ws;                 // Q | K | V^T, each BT*DK bf16
    char* Pbase   = (char*)d_ws + QKV_BYTES;         // 1120 slots x 8704 B (~9.7 MB)
    ushort_t* WtG = (ushort_t*)d_out;                // Wt scratch, overwritten by attn

    wt_prep_kernel<<<96, 256, 0, stream>>>(Wq, Wk, Wv, WtG);
    qkv_mfma_kernel<<<512, 256, 0, stream>>>(X, WtG, bq, bk, bv, QKV);
    attn_seg_kernel<<<576, 256, 0, stream>>>(QKV, Out, Pbase);
    attn_combine_kernel<<<224, 256, 0, stream>>>(Pbase, Out);
}